// Round 1
// baseline (7883.130 us; speedup 1.0000x reference)
//
#include <hip/hip_runtime.h>
#include <math.h>

#define NN   20000
#define TT   32
#define INF_ 32
#define HID  64
#define NH   4
#define EE   320000
#define ETOT (EE + NN)

static __device__ __forceinline__ float sigf(float x){ return 1.0f/(1.0f+__expf(-x)); }
static __device__ __forceinline__ float tanhf_(float x){ float e=__expf(2.0f*x); return 1.0f - 2.0f/(e+1.0f); }
static __device__ __forceinline__ float lrelu(float x){ return x>0.0f ? x : 0.2f*x; }
static __device__ __forceinline__ unsigned fkey(float f){ unsigned u=__float_as_uint(f); return (u&0x80000000u)? ~u : (u|0x80000000u); }
static __device__ __forceinline__ float funkey(unsigned k){ return __uint_as_float((k&0x80000000u)? (k^0x80000000u) : ~k); }

static __device__ __forceinline__ void edge_sd(const int* __restrict__ ei, int e, int& s, int& d){
  if (e < EE){ s = ei[e]; d = ei[EE + e]; } else { s = e - EE; d = s; }
}

// ---------------- utility kernels ----------------
__global__ void kzero(float* __restrict__ p, long n){
  long i = (long)blockIdx.x*256 + threadIdx.x;
  long st = (long)gridDim.x*256;
  for (; i < n; i += st) p[i] = 0.f;
}

__global__ void pack_weights(const float* __restrict__ Wih0, const float* __restrict__ Whh0,
                             const float* __restrict__ bih0, const float* __restrict__ bhh0,
                             const float* __restrict__ Wih1, const float* __restrict__ Whh1,
                             const float* __restrict__ bih1, const float* __restrict__ bhh1,
                             float* __restrict__ W0T, float* __restrict__ W1T,
                             float* __restrict__ b0, float* __restrict__ b1){
  int i = blockIdx.x*256 + threadIdx.x;
  if (i < 96*256){
    int k = i >> 8, r = i & 255;
    W0T[i] = (k < 32) ? Wih0[r*32 + k] : Whh0[r*64 + (k-32)];
  }
  int j = i - 96*256;
  if (j >= 0 && j < 128*256){
    int k = j >> 8, r = j & 255;
    W1T[j] = (k < 64) ? Wih1[r*64 + k] : Whh1[r*64 + (k-64)];
  }
  int m = i - (96*256 + 128*256);
  if (m >= 0 && m < 256)   b0[m] = bih0[m] + bhh0[m];
  if (m >= 256 && m < 512) b1[m-256] = bih1[m-256] + bhh1[m-256];
}

// ---------------- fused 2-layer LSTM ----------------
// block = 256 thr = 4 waves; 64 nodes/block; wave q computes gate-type-q rows
// (wave-uniform -> weights via scalar loads). h kept in LDS [unit][node].
__global__ __launch_bounds__(256, 2) void lstm_fused(
    const float* __restrict__ x,
    const float* __restrict__ W0T, const float* __restrict__ W1T,
    const float* __restrict__ b0,  const float* __restrict__ b1,
    float* __restrict__ h1out)
{
  __shared__ float g_lds[4][32][64];   // 32KB gate exchange (half the units at a time)
  __shared__ float h0_lds[64][64];     // 16KB [unit][node]
  __shared__ float h1_lds[64][64];     // 16KB

  const int tid  = threadIdx.x;
  const int lane = tid & 63;
  const int wq   = __builtin_amdgcn_readfirstlane(tid >> 6);
  const int gbase = blockIdx.x * 64;
  const int n = gbase + lane;
  const int nclamp = (n < NN) ? n : 0;

  float c0[16], c1[16];
#pragma unroll
  for (int i=0;i<16;i++){ c0[i]=0.f; c1[i]=0.f; }
  for (int i=tid;i<64*64;i+=256){ ((float*)h0_lds)[i]=0.f; ((float*)h1_lds)[i]=0.f; }
  __syncthreads();

  const float4* __restrict__ xp = (const float4*)(x + (size_t)nclamp*(TT*INF_));
  const float* bq0 = b0 + wq*64;
  const float* bq1 = b1 + wq*64;
  const float* W0  = W0T + wq*64;
  const float* W1  = W1T + wq*64;

  for (int t=0; t<TT; ++t){
    // ---- load x_t into registers (per-lane contiguous 128B) ----
    float xr[INF_];
#pragma unroll
    for (int i=0;i<8;i++){
      float4 v = xp[t*8 + i];
      xr[4*i+0]=v.x; xr[4*i+1]=v.y; xr[4*i+2]=v.z; xr[4*i+3]=v.w;
    }

    // ---- layer 0 gates: rows wq*64..+63 ----
    float acc[64];
#pragma unroll
    for (int j=0;j<64;j++) acc[j] = bq0[j];
    for (int k=0;k<INF_;k++){
      const float xv = xr[k];
      const float* wk = W0 + k*256;
#pragma unroll
      for (int j=0;j<64;j++) acc[j] = fmaf(wk[j], xv, acc[j]);
    }
    for (int k=0;k<HID;k++){
      const float hv = h0_lds[k][lane];
      const float* wk = W0 + (INF_+k)*256;
#pragma unroll
      for (int j=0;j<64;j++) acc[j] = fmaf(wk[j], hv, acc[j]);
    }
    // ---- exchange + pointwise update (2 chunks of 32 units) ----
#pragma unroll
    for (int ch=0; ch<2; ++ch){
      __syncthreads();
#pragma unroll
      for (int j=0;j<32;j++) g_lds[wq][j][lane] = acc[ch*32+j];
      __syncthreads();
#pragma unroll
      for (int i=0;i<8;i++){
        const int ul = wq*8 + i;
        const int uu = ch*32 + ul;
        const float gi = g_lds[0][ul][lane];
        const float gf = g_lds[1][ul][lane];
        const float gg = g_lds[2][ul][lane];
        const float go = g_lds[3][ul][lane];
        const int ci = ch*8 + i;
        const float cc = sigf(gf)*c0[ci] + sigf(gi)*tanhf_(gg);
        c0[ci] = cc;
        h0_lds[uu][lane] = sigf(go)*tanhf_(cc);
      }
    }
    __syncthreads();

    // ---- layer 1 gates (input = new h0) ----
#pragma unroll
    for (int j=0;j<64;j++) acc[j] = bq1[j];
    for (int k=0;k<HID;k++){
      const float hv = h0_lds[k][lane];
      const float* wk = W1 + k*256;
#pragma unroll
      for (int j=0;j<64;j++) acc[j] = fmaf(wk[j], hv, acc[j]);
    }
    for (int k=0;k<HID;k++){
      const float hv = h1_lds[k][lane];
      const float* wk = W1 + (HID+k)*256;
#pragma unroll
      for (int j=0;j<64;j++) acc[j] = fmaf(wk[j], hv, acc[j]);
    }
#pragma unroll
    for (int ch=0; ch<2; ++ch){
      __syncthreads();
#pragma unroll
      for (int j=0;j<32;j++) g_lds[wq][j][lane] = acc[ch*32+j];
      __syncthreads();
#pragma unroll
      for (int i=0;i<8;i++){
        const int ul = wq*8 + i;
        const int uu = ch*32 + ul;
        const float gi = g_lds[0][ul][lane];
        const float gf = g_lds[1][ul][lane];
        const float gg = g_lds[2][ul][lane];
        const float go = g_lds[3][ul][lane];
        const int ci = ch*8 + i;
        const float cc = sigf(gf)*c1[ci] + sigf(gi)*tanhf_(gg);
        c1[ci] = cc;
        h1_lds[uu][lane] = sigf(go)*tanhf_(cc);
      }
    }
  }
  __syncthreads();
  for (int i=tid;i<64*64;i+=256){
    const int nn = i>>6, u = i&63;
    if (gbase+nn < NN) h1out[(size_t)(gbase+nn)*64 + u] = h1_lds[u][nn];
  }
}

// ---------------- GAT layer 1 ----------------
// per node: xh = h @ W (256 outs), al_s/al_d head dots (wave = head)
__global__ __launch_bounds__(256) void gat1_prep(const float* __restrict__ h1, const float* __restrict__ W,
  const float* __restrict__ as_, const float* __restrict__ ad_,
  float* __restrict__ xh, float* __restrict__ als, float* __restrict__ ald)
{
  const int nb = blockIdx.x;
  const int o  = threadIdx.x;
  const int q  = o >> 6, u = o & 63;
  const float* hp = h1 + (size_t)nb*64;
  float acc = 0.f;
#pragma unroll 8
  for (int k=0;k<64;k++) acc = fmaf(hp[k], W[k*256 + o], acc);
  xh[(size_t)nb*256 + o] = acc;
  float ps = acc * as_[o];
  float pd = acc * ad_[o];
#pragma unroll
  for (int off=32; off>=1; off>>=1){ ps += __shfl_xor(ps, off); pd += __shfl_xor(pd, off); }
  if (u == 0){ als[nb*4 + q] = ps; ald[nb*4 + q] = pd; }
}

__global__ void gat1_max(const int* __restrict__ ei, const float* __restrict__ als,
                         const float* __restrict__ ald, unsigned* __restrict__ mk){
  int id = blockIdx.x*256 + threadIdx.x;
  if (id >= ETOT*NH) return;
  int e = id >> 2, q = id & 3, s, d;
  edge_sd(ei, e, s, d);
  float ev = lrelu(als[s*4+q] + ald[d*4+q]);
  atomicMax(mk + d*4+q, fkey(ev));
}

__global__ void gat1_den(const int* __restrict__ ei, const float* __restrict__ als,
                         const float* __restrict__ ald, const unsigned* __restrict__ mk,
                         float* __restrict__ den){
  int id = blockIdx.x*256 + threadIdx.x;
  if (id >= ETOT*NH) return;
  int e = id >> 2, q = id & 3, s, d;
  edge_sd(ei, e, s, d);
  float ev = lrelu(als[s*4+q] + ald[d*4+q]);
  float ex = __expf(ev - funkey(mk[d*4+q]));
  unsafeAtomicAdd(den + d*4+q, ex);
}

__global__ void gat1_agg(const int* __restrict__ ei, const float* __restrict__ als,
                         const float* __restrict__ ald, const unsigned* __restrict__ mk,
                         const float* __restrict__ xh, float* __restrict__ U){
  int id = blockIdx.x*256 + threadIdx.x;
  if (id >= ETOT*NH) return;
  int e = id >> 2, q = id & 3, s, d;
  edge_sd(ei, e, s, d);
  float ev = lrelu(als[s*4+q] + ald[d*4+q]);
  float ex = __expf(ev - funkey(mk[d*4+q]));
  const float4* xp = (const float4*)(xh + (size_t)s*256 + q*64);
  float* up = U + (size_t)d*256 + q*64;
#pragma unroll
  for (int i=0;i<16;i++){
    float4 v = xp[i];
    unsafeAtomicAdd(up+4*i+0, ex*v.x);
    unsafeAtomicAdd(up+4*i+1, ex*v.y);
    unsafeAtomicAdd(up+4*i+2, ex*v.z);
    unsafeAtomicAdd(up+4*i+3, ex*v.w);
  }
}

// ---------------- GAT layer 2 prep: relu(out1)+proj to scalar ----------------
__global__ __launch_bounds__(256) void gat2_prep(const float* __restrict__ U, const float* __restrict__ den1,
   const float* __restrict__ b1g, const float* __restrict__ w2,
   const float* __restrict__ as2, const float* __restrict__ ad2,
   float* __restrict__ xh2, float* __restrict__ a2s, float* __restrict__ a2d)
{
  const int nb = blockIdx.x*4 + (threadIdx.x >> 6);
  const int u  = threadIdx.x & 63;
  if (nb >= NN) return;
  float acc = 0.f;
#pragma unroll
  for (int i=0;i<4;i++){
    const int o = i*64 + u;
    float v = U[(size_t)nb*256 + o] / (den1[nb*4 + i] + 1e-16f) + b1g[o];
    v = v > 0.f ? v : 0.f;
    acc = fmaf(v, w2[o], acc);
  }
#pragma unroll
  for (int off=32; off>=1; off>>=1) acc += __shfl_xor(acc, off);
  if (u == 0){ xh2[nb] = acc; a2s[nb] = acc*as2[0]; a2d[nb] = acc*ad2[0]; }
}

__global__ void gat2_max(const int* __restrict__ ei, const float* __restrict__ a2s,
                         const float* __restrict__ a2d, unsigned* __restrict__ mk){
  int e = blockIdx.x*256 + threadIdx.x;
  if (e >= ETOT) return;
  int s, d; edge_sd(ei, e, s, d);
  float ev = lrelu(a2s[s] + a2d[d]);
  atomicMax(mk + d, fkey(ev));
}

__global__ void gat2_den(const int* __restrict__ ei, const float* __restrict__ a2s,
                         const float* __restrict__ a2d, const unsigned* __restrict__ mk,
                         float* __restrict__ den){
  int e = blockIdx.x*256 + threadIdx.x;
  if (e >= ETOT) return;
  int s, d; edge_sd(ei, e, s, d);
  float ev = lrelu(a2s[s] + a2d[d]);
  unsafeAtomicAdd(den + d, __expf(ev - funkey(mk[d])));
}

__global__ void gat2_agg(const int* __restrict__ ei, const float* __restrict__ a2s,
                         const float* __restrict__ a2d, const unsigned* __restrict__ mk,
                         const float* __restrict__ xh2, float* __restrict__ U2){
  int e = blockIdx.x*256 + threadIdx.x;
  if (e >= ETOT) return;
  int s, d; edge_sd(ei, e, s, d);
  float ev = lrelu(a2s[s] + a2d[d]);
  float ex = __expf(ev - funkey(mk[d]));
  unsafeAtomicAdd(U2 + d, ex * xh2[s]);
}

__global__ void fin(const float* __restrict__ U2, const float* __restrict__ den2,
                    const float* __restrict__ b2, float* __restrict__ out){
  int n = blockIdx.x*256 + threadIdx.x;
  if (n >= NN) return;
  out[n] = U2[n] / (den2[n] + 1e-16f) + b2[0];
}

// ---------------- launcher ----------------
extern "C" void kernel_launch(void* const* d_in, const int* in_sizes, int n_in,
                              void* d_out, int out_size, void* d_ws, size_t ws_size,
                              hipStream_t stream)
{
  const float* x    = (const float*)d_in[0];
  const int*   ei   = (const int*)d_in[1];
  const float* Wih0 = (const float*)d_in[2];
  const float* Whh0 = (const float*)d_in[3];
  const float* bih0 = (const float*)d_in[4];
  const float* bhh0 = (const float*)d_in[5];
  const float* Wih1 = (const float*)d_in[6];
  const float* Whh1 = (const float*)d_in[7];
  const float* bih1 = (const float*)d_in[8];
  const float* bhh1 = (const float*)d_in[9];
  const float* g1w  = (const float*)d_in[10];
  const float* g1as = (const float*)d_in[11];
  const float* g1ad = (const float*)d_in[12];
  const float* g1b  = (const float*)d_in[13];
  const float* g2w  = (const float*)d_in[14];
  const float* g2as = (const float*)d_in[15];
  const float* g2ad = (const float*)d_in[16];
  const float* g2b  = (const float*)d_in[17];

  float* ws  = (float*)d_ws;
  float* W0T = ws;                    // 96*256
  float* W1T = W0T + 96*256;          // 128*256
  float* b0  = W1T + 128*256;         // 256
  float* b1  = b0 + 256;              // 256
  float* h1  = b1 + 256;              // 20000*64
  float* xh  = h1 + 1280000;          // 20000*256
  float* als = xh + 5120000;          // 80000
  float* ald = als + 80000;           // 80000
  float* xh2 = ald + 80000;           // 20000
  float* a2s = xh2 + 20000;           // 20000
  float* a2d = a2s + 20000;           // 20000
  float* zb  = a2d + 20000;           // ---- zeroed region ----
  unsigned* m1k = (unsigned*)zb;      // 80000
  float* den1 = zb + 80000;           // 80000
  float* U1   = den1 + 80000;         // 20000*256
  unsigned* m2k = (unsigned*)(U1 + 5120000); // 20000
  float* den2 = U1 + 5120000 + 20000; // 20000
  float* U2   = den2 + 20000;         // 20000
  const long ZCOUNT = 80000L + 80000 + 5120000 + 20000 + 20000 + 20000;

  kzero<<<2048, 256, 0, stream>>>(zb, ZCOUNT);
  pack_weights<<<226, 256, 0, stream>>>(Wih0,Whh0,bih0,bhh0,Wih1,Whh1,bih1,bhh1,W0T,W1T,b0,b1);
  lstm_fused<<<313, 256, 0, stream>>>(x, W0T, W1T, b0, b1, h1);
  gat1_prep<<<NN, 256, 0, stream>>>(h1, g1w, g1as, g1ad, xh, als, ald);
  gat1_max<<<(ETOT*NH+255)/256, 256, 0, stream>>>(ei, als, ald, m1k);
  gat1_den<<<(ETOT*NH+255)/256, 256, 0, stream>>>(ei, als, ald, m1k, den1);
  gat1_agg<<<(ETOT*NH+255)/256, 256, 0, stream>>>(ei, als, ald, m1k, xh, U1);
  gat2_prep<<<NN/4, 256, 0, stream>>>(U1, den1, g1b, g2w, g2as, g2ad, xh2, a2s, a2d);
  gat2_max<<<(ETOT+255)/256, 256, 0, stream>>>(ei, a2s, a2d, m2k);
  gat2_den<<<(ETOT+255)/256, 256, 0, stream>>>(ei, a2s, a2d, m2k, den2);
  gat2_agg<<<(ETOT+255)/256, 256, 0, stream>>>(ei, a2s, a2d, m2k, xh2, U2);
  fin<<<(NN+255)/256, 256, 0, stream>>>(U2, den2, g2b, (float*)d_out);
}

// Round 2
// 3389.672 us; speedup vs baseline: 2.3256x; 2.3256x over previous
//
#include <hip/hip_runtime.h>
#include <math.h>

#define NN   20000
#define TT   32
#define INF_ 32
#define HID  64
#define NH   4
#define EE   320000
#define ETOT (EE + NN)

static __device__ __forceinline__ float sigf(float x){ return 1.0f/(1.0f+__expf(-x)); }
static __device__ __forceinline__ float tanhf_(float x){ float e=__expf(2.0f*x); return 1.0f - 2.0f/(e+1.0f); }
static __device__ __forceinline__ float lrelu(float x){ return x>0.0f ? x : 0.2f*x; }

static __device__ __forceinline__ void edge_sd(const int* __restrict__ ei, int e, int& s, int& d){
  if (e < EE){ s = ei[e]; d = ei[EE + e]; } else { s = e - EE; d = s; }
}

// ---------------- utility kernels ----------------
__global__ void kzero_int(int* __restrict__ p, int n){
  int i = blockIdx.x*256 + threadIdx.x;
  if (i < n) p[i] = 0;
}

__global__ void pack_weights(const float* __restrict__ Wih0, const float* __restrict__ Whh0,
                             const float* __restrict__ bih0, const float* __restrict__ bhh0,
                             const float* __restrict__ Wih1, const float* __restrict__ Whh1,
                             const float* __restrict__ bih1, const float* __restrict__ bhh1,
                             float* __restrict__ W0T, float* __restrict__ W1T,
                             float* __restrict__ b0, float* __restrict__ b1){
  int i = blockIdx.x*256 + threadIdx.x;
  if (i < 96*256){
    int k = i >> 8, r = i & 255;
    W0T[i] = (k < 32) ? Wih0[r*32 + k] : Whh0[r*64 + (k-32)];
  }
  int j = i - 96*256;
  if (j >= 0 && j < 128*256){
    int k = j >> 8, r = j & 255;
    W1T[j] = (k < 64) ? Wih1[r*64 + k] : Whh1[r*64 + (k-64)];
  }
  int m = i - (96*256 + 128*256);
  if (m >= 0 && m < 256)   b0[m] = bih0[m] + bhh0[m];
  if (m >= 256 && m < 512) b1[m-256] = bih1[m-256] + bhh1[m-256];
}

// ---------------- CSR build (dst-indexed) ----------------
__global__ void count_deg(const int* __restrict__ ei, int* __restrict__ deg){
  int e = blockIdx.x*256 + threadIdx.x;
  if (e >= ETOT) return;
  int s, d; edge_sd(ei, e, s, d);
  atomicAdd(deg + d, 1);
}

__global__ void scan_deg(const int* __restrict__ deg, int* __restrict__ indptr, int* __restrict__ cursor){
  __shared__ int part[256];
  const int t = threadIdx.x;
  const int CH = (NN + 255) / 256;            // 79
  const int c0 = t * CH;
  int sum = 0;
  for (int i=0;i<CH;i++){ int idx=c0+i; if (idx<NN) sum += deg[idx]; }
  part[t] = sum; __syncthreads();
  int val = sum;
  for (int off=1; off<256; off<<=1){
    int add = (t>=off) ? part[t-off] : 0;
    __syncthreads();
    val += add; part[t] = val;
    __syncthreads();
  }
  int run = val - sum;                        // exclusive prefix
  for (int i=0;i<CH;i++){
    int idx=c0+i;
    if (idx<NN){ indptr[idx]=run; cursor[idx]=run; run += deg[idx]; }
  }
  if (t == 0) indptr[NN] = ETOT;
}

__global__ void scatter_edges(const int* __restrict__ ei, int* __restrict__ cursor, int* __restrict__ csr_src){
  int e = blockIdx.x*256 + threadIdx.x;
  if (e >= ETOT) return;
  int s, d; edge_sd(ei, e, s, d);
  int pos = atomicAdd(cursor + d, 1);
  csr_src[pos] = s;
}

// ---------------- fused 2-layer LSTM ----------------
__global__ __launch_bounds__(256, 2) void lstm_fused(
    const float* __restrict__ x,
    const float* __restrict__ W0T, const float* __restrict__ W1T,
    const float* __restrict__ b0,  const float* __restrict__ b1,
    float* __restrict__ h1out)
{
  __shared__ float g_lds[4][32][64];
  __shared__ float h0_lds[64][64];
  __shared__ float h1_lds[64][64];

  const int tid  = threadIdx.x;
  const int lane = tid & 63;
  const int wq   = __builtin_amdgcn_readfirstlane(tid >> 6);
  const int gbase = blockIdx.x * 64;
  const int n = gbase + lane;
  const int nclamp = (n < NN) ? n : 0;

  float c0[16], c1[16];
#pragma unroll
  for (int i=0;i<16;i++){ c0[i]=0.f; c1[i]=0.f; }
  for (int i=tid;i<64*64;i+=256){ ((float*)h0_lds)[i]=0.f; ((float*)h1_lds)[i]=0.f; }
  __syncthreads();

  const float4* __restrict__ xp = (const float4*)(x + (size_t)nclamp*(TT*INF_));
  const float* bq0 = b0 + wq*64;
  const float* bq1 = b1 + wq*64;
  const float* W0  = W0T + wq*64;
  const float* W1  = W1T + wq*64;

  for (int t=0; t<TT; ++t){
    float xr[INF_];
#pragma unroll
    for (int i=0;i<8;i++){
      float4 v = xp[t*8 + i];
      xr[4*i+0]=v.x; xr[4*i+1]=v.y; xr[4*i+2]=v.z; xr[4*i+3]=v.w;
    }

    float acc[64];
#pragma unroll
    for (int j=0;j<64;j++) acc[j] = bq0[j];
    for (int k=0;k<INF_;k++){
      const float xv = xr[k];
      const float* wk = W0 + k*256;
#pragma unroll
      for (int j=0;j<64;j++) acc[j] = fmaf(wk[j], xv, acc[j]);
    }
    for (int k=0;k<HID;k++){
      const float hv = h0_lds[k][lane];
      const float* wk = W0 + (INF_+k)*256;
#pragma unroll
      for (int j=0;j<64;j++) acc[j] = fmaf(wk[j], hv, acc[j]);
    }
#pragma unroll
    for (int ch=0; ch<2; ++ch){
      __syncthreads();
#pragma unroll
      for (int j=0;j<32;j++) g_lds[wq][j][lane] = acc[ch*32+j];
      __syncthreads();
#pragma unroll
      for (int i=0;i<8;i++){
        const int ul = wq*8 + i;
        const int uu = ch*32 + ul;
        const float gi = g_lds[0][ul][lane];
        const float gf = g_lds[1][ul][lane];
        const float gg = g_lds[2][ul][lane];
        const float go = g_lds[3][ul][lane];
        const int ci = ch*8 + i;
        const float cc = sigf(gf)*c0[ci] + sigf(gi)*tanhf_(gg);
        c0[ci] = cc;
        h0_lds[uu][lane] = sigf(go)*tanhf_(cc);
      }
    }
    __syncthreads();

#pragma unroll
    for (int j=0;j<64;j++) acc[j] = bq1[j];
    for (int k=0;k<HID;k++){
      const float hv = h0_lds[k][lane];
      const float* wk = W1 + k*256;
#pragma unroll
      for (int j=0;j<64;j++) acc[j] = fmaf(wk[j], hv, acc[j]);
    }
    for (int k=0;k<HID;k++){
      const float hv = h1_lds[k][lane];
      const float* wk = W1 + (HID+k)*256;
#pragma unroll
      for (int j=0;j<64;j++) acc[j] = fmaf(wk[j], hv, acc[j]);
    }
#pragma unroll
    for (int ch=0; ch<2; ++ch){
      __syncthreads();
#pragma unroll
      for (int j=0;j<32;j++) g_lds[wq][j][lane] = acc[ch*32+j];
      __syncthreads();
#pragma unroll
      for (int i=0;i<8;i++){
        const int ul = wq*8 + i;
        const int uu = ch*32 + ul;
        const float gi = g_lds[0][ul][lane];
        const float gf = g_lds[1][ul][lane];
        const float gg = g_lds[2][ul][lane];
        const float go = g_lds[3][ul][lane];
        const int ci = ch*8 + i;
        const float cc = sigf(gf)*c1[ci] + sigf(gi)*tanhf_(gg);
        c1[ci] = cc;
        h1_lds[uu][lane] = sigf(go)*tanhf_(cc);
      }
    }
  }
  __syncthreads();
  for (int i=tid;i<64*64;i+=256){
    const int nn = i>>6, u = i&63;
    if (gbase+nn < NN) h1out[(size_t)(gbase+nn)*64 + u] = h1_lds[u][nn];
  }
}

// ---------------- GAT layer 1 prep ----------------
__global__ __launch_bounds__(256) void gat1_prep(const float* __restrict__ h1, const float* __restrict__ W,
  const float* __restrict__ as_, const float* __restrict__ ad_,
  float* __restrict__ xh, float* __restrict__ als, float* __restrict__ ald)
{
  const int nb = blockIdx.x;
  const int o  = threadIdx.x;
  const int q  = o >> 6, u = o & 63;
  const float* hp = h1 + (size_t)nb*64;
  float acc = 0.f;
#pragma unroll 8
  for (int k=0;k<64;k++) acc = fmaf(hp[k], W[k*256 + o], acc);
  xh[(size_t)nb*256 + o] = acc;
  float ps = acc * as_[o];
  float pd = acc * ad_[o];
#pragma unroll
  for (int off=32; off>=1; off>>=1){ ps += __shfl_xor(ps, off); pd += __shfl_xor(pd, off); }
  if (u == 0){ als[nb*4 + q] = ps; ald[nb*4 + q] = pd; }
}

// ---------------- GAT1 gather: softmax-agg + norm + bias + relu + g2 projection ----------------
// one wave per dst node
__global__ __launch_bounds__(256) void gat1_gather(
  const int* __restrict__ indptr, const int* __restrict__ csr_src,
  const float* __restrict__ als, const float* __restrict__ ald,
  const float* __restrict__ xh,  const float* __restrict__ b1g,
  const float* __restrict__ w2,  const float* __restrict__ as2, const float* __restrict__ ad2,
  float* __restrict__ xh2, float* __restrict__ a2s, float* __restrict__ a2d)
{
  const int d = blockIdx.x*4 + (threadIdx.x >> 6);
  const int lane = threadIdx.x & 63;
  if (d >= NN) return;
  const int p0 = indptr[d], p1 = indptr[d+1];

  float aldv[4];
#pragma unroll
  for (int q=0;q<4;q++) aldv[q] = ald[d*4+q];

  // pass 1: per-head max
  float mx[4];
#pragma unroll
  for (int q=0;q<4;q++) mx[q] = -3.4e38f;
  for (int e=p0+lane; e<p1; e+=64){
    int s = csr_src[e];
#pragma unroll
    for (int q=0;q<4;q++){
      float ev = lrelu(als[s*4+q] + aldv[q]);
      mx[q] = fmaxf(mx[q], ev);
    }
  }
#pragma unroll
  for (int off=32; off>=1; off>>=1){
#pragma unroll
    for (int q=0;q<4;q++) mx[q] = fmaxf(mx[q], __shfl_xor(mx[q], off));
  }

  // pass 2: weighted aggregation. lane owns outputs lane*4..lane*4+3, head q=lane>>4
  const int q = lane >> 4;
  const float mq = mx[q];
  const float aldq = aldv[q];
  float ax=0.f, ay=0.f, az=0.f, aw=0.f, den=0.f;
  int s_next = (p0 < p1) ? csr_src[p0] : 0;
  for (int e=p0; e<p1; ++e){
    const int s = s_next;
    if (e+1 < p1) s_next = csr_src[e+1];
    float ev = lrelu(als[s*4+q] + aldq);
    float ex = __expf(ev - mq);
    den += ex;
    float4 v = *(const float4*)(xh + (size_t)s*256 + lane*4);
    ax = fmaf(ex, v.x, ax); ay = fmaf(ex, v.y, ay);
    az = fmaf(ex, v.z, az); aw = fmaf(ex, v.w, aw);
  }
  const float r = 1.0f/(den + 1e-16f);
  const int o = lane*4;
  float v0 = fmaf(ax, r, 0.f) + b1g[o+0];
  float v1 = fmaf(ay, r, 0.f) + b1g[o+1];
  float v2 = fmaf(az, r, 0.f) + b1g[o+2];
  float v3 = fmaf(aw, r, 0.f) + b1g[o+3];
  v0 = v0>0.f?v0:0.f; v1 = v1>0.f?v1:0.f; v2 = v2>0.f?v2:0.f; v3 = v3>0.f?v3:0.f;
  float part = v0*w2[o+0] + v1*w2[o+1] + v2*w2[o+2] + v3*w2[o+3];
#pragma unroll
  for (int off=32; off>=1; off>>=1) part += __shfl_xor(part, off);
  if (lane == 0){
    xh2[d] = part;
    a2s[d] = part * as2[0];
    a2d[d] = part * ad2[0];
  }
}

// ---------------- GAT2 gather: scalar features, writes output ----------------
__global__ __launch_bounds__(256) void gat2_gather(
  const int* __restrict__ indptr, const int* __restrict__ csr_src,
  const float* __restrict__ a2s, const float* __restrict__ a2d,
  const float* __restrict__ xh2, const float* __restrict__ b2,
  float* __restrict__ out)
{
  const int d = blockIdx.x*4 + (threadIdx.x >> 6);
  const int lane = threadIdx.x & 63;
  if (d >= NN) return;
  const int p0 = indptr[d], p1 = indptr[d+1];
  const float add = a2d[d];

  float mx = -3.4e38f;
  for (int e=p0+lane; e<p1; e+=64){
    int s = csr_src[e];
    mx = fmaxf(mx, lrelu(a2s[s] + add));
  }
#pragma unroll
  for (int off=32; off>=1; off>>=1) mx = fmaxf(mx, __shfl_xor(mx, off));

  float den = 0.f, num = 0.f;
  for (int e=p0+lane; e<p1; e+=64){
    int s = csr_src[e];
    float ev = lrelu(a2s[s] + add);
    float ex = __expf(ev - mx);
    den += ex;
    num = fmaf(ex, xh2[s], num);
  }
#pragma unroll
  for (int off=32; off>=1; off>>=1){ den += __shfl_xor(den, off); num += __shfl_xor(num, off); }
  if (lane == 0) out[d] = num/(den + 1e-16f) + b2[0];
}

// ---------------- launcher ----------------
extern "C" void kernel_launch(void* const* d_in, const int* in_sizes, int n_in,
                              void* d_out, int out_size, void* d_ws, size_t ws_size,
                              hipStream_t stream)
{
  const float* x    = (const float*)d_in[0];
  const int*   ei   = (const int*)d_in[1];
  const float* Wih0 = (const float*)d_in[2];
  const float* Whh0 = (const float*)d_in[3];
  const float* bih0 = (const float*)d_in[4];
  const float* bhh0 = (const float*)d_in[5];
  const float* Wih1 = (const float*)d_in[6];
  const float* Whh1 = (const float*)d_in[7];
  const float* bih1 = (const float*)d_in[8];
  const float* bhh1 = (const float*)d_in[9];
  const float* g1w  = (const float*)d_in[10];
  const float* g1as = (const float*)d_in[11];
  const float* g1ad = (const float*)d_in[12];
  const float* g1b  = (const float*)d_in[13];
  const float* g2w  = (const float*)d_in[14];
  const float* g2as = (const float*)d_in[15];
  const float* g2ad = (const float*)d_in[16];
  const float* g2b  = (const float*)d_in[17];

  float* ws  = (float*)d_ws;
  float* W0T = ws;                    // 96*256
  float* W1T = W0T + 96*256;          // 128*256
  float* b0  = W1T + 128*256;         // 256
  float* b1  = b0 + 256;              // 256
  float* h1  = b1 + 256;              // 20000*64
  float* xh  = h1 + 1280000;          // 20000*256
  float* als = xh + 5120000;          // 80000
  float* ald = als + 80000;           // 80000
  float* xh2 = ald + 80000;           // 20000
  float* a2s = xh2 + 20000;           // 20000
  float* a2d = a2s + 20000;           // 20000
  int*   deg    = (int*)(a2d + 20000);   // 20000
  int*   indptr = deg + 20000;           // 20001
  int*   cursor = indptr + 20001;        // 20000
  int*   csr    = cursor + 20000;        // 340000

  kzero_int<<<(NN+255)/256, 256, 0, stream>>>(deg, NN);
  pack_weights<<<226, 256, 0, stream>>>(Wih0,Whh0,bih0,bhh0,Wih1,Whh1,bih1,bhh1,W0T,W1T,b0,b1);
  count_deg<<<(ETOT+255)/256, 256, 0, stream>>>(ei, deg);
  scan_deg<<<1, 256, 0, stream>>>(deg, indptr, cursor);
  scatter_edges<<<(ETOT+255)/256, 256, 0, stream>>>(ei, cursor, csr);
  lstm_fused<<<313, 256, 0, stream>>>(x, W0T, W1T, b0, b1, h1);
  gat1_prep<<<NN, 256, 0, stream>>>(h1, g1w, g1as, g1ad, xh, als, ald);
  gat1_gather<<<(NN+3)/4, 256, 0, stream>>>(indptr, csr, als, ald, xh, g1b, g2w, g2as, g2ad, xh2, a2s, a2d);
  gat2_gather<<<(NN+3)/4, 256, 0, stream>>>(indptr, csr, a2s, a2d, xh2, g2b, (float*)d_out);
}

// Round 3
// 2010.832 us; speedup vs baseline: 3.9203x; 1.6857x over previous
//
#include <hip/hip_runtime.h>
#include <math.h>

#define NN   20000
#define TT   32
#define INF_ 32
#define HID  64
#define NH   4
#define EE   320000
#define ETOT (EE + NN)

static __device__ __forceinline__ float sigf(float x){ return 1.0f/(1.0f+__expf(-x)); }
static __device__ __forceinline__ float tanhf_(float x){ float e=__expf(2.0f*x); return 1.0f - 2.0f/(e+1.0f); }
static __device__ __forceinline__ float lrelu(float x){ return x>0.0f ? x : 0.2f*x; }

static __device__ __forceinline__ void edge_sd(const int* __restrict__ ei, int e, int& s, int& d){
  if (e < EE){ s = ei[e]; d = ei[EE + e]; } else { s = e - EE; d = s; }
}

// ---------------- utility kernels ----------------
__global__ void kzero_int(int* __restrict__ p, int n){
  int i = blockIdx.x*256 + threadIdx.x;
  if (i < n) p[i] = 0;
}

__global__ void pack_weights(const float* __restrict__ Wih0, const float* __restrict__ Whh0,
                             const float* __restrict__ bih0, const float* __restrict__ bhh0,
                             const float* __restrict__ Wih1, const float* __restrict__ Whh1,
                             const float* __restrict__ bih1, const float* __restrict__ bhh1,
                             float* __restrict__ W0T, float* __restrict__ W1T,
                             float* __restrict__ b0, float* __restrict__ b1){
  int i = blockIdx.x*256 + threadIdx.x;
  if (i < 96*256){
    int k = i >> 8, r = i & 255;
    W0T[i] = (k < 32) ? Wih0[r*32 + k] : Whh0[r*64 + (k-32)];
  }
  int j = i - 96*256;
  if (j >= 0 && j < 128*256){
    int k = j >> 8, r = j & 255;
    W1T[j] = (k < 64) ? Wih1[r*64 + k] : Whh1[r*64 + (k-64)];
  }
  int m = i - (96*256 + 128*256);
  if (m >= 0 && m < 256)   b0[m] = bih0[m] + bhh0[m];
  if (m >= 256 && m < 512) b1[m-256] = bih1[m-256] + bhh1[m-256];
}

// ---------------- CSR build (dst-indexed) ----------------
__global__ void count_deg(const int* __restrict__ ei, int* __restrict__ deg){
  int e = blockIdx.x*256 + threadIdx.x;
  if (e >= ETOT) return;
  int s, d; edge_sd(ei, e, s, d);
  atomicAdd(deg + d, 1);
}

__global__ void scan_deg(const int* __restrict__ deg, int* __restrict__ indptr, int* __restrict__ cursor){
  __shared__ int part[256];
  const int t = threadIdx.x;
  const int CH = (NN + 255) / 256;
  const int c0 = t * CH;
  int sum = 0;
  for (int i=0;i<CH;i++){ int idx=c0+i; if (idx<NN) sum += deg[idx]; }
  part[t] = sum; __syncthreads();
  int val = sum;
  for (int off=1; off<256; off<<=1){
    int add = (t>=off) ? part[t-off] : 0;
    __syncthreads();
    val += add; part[t] = val;
    __syncthreads();
  }
  int run = val - sum;
  for (int i=0;i<CH;i++){
    int idx=c0+i;
    if (idx<NN){ indptr[idx]=run; cursor[idx]=run; run += deg[idx]; }
  }
  if (t == 0) indptr[NN] = ETOT;
}

__global__ void scatter_edges(const int* __restrict__ ei, int* __restrict__ cursor, int* __restrict__ csr_src){
  int e = blockIdx.x*256 + threadIdx.x;
  if (e >= ETOT) return;
  int s, d; edge_sd(ei, e, s, d);
  int pos = atomicAdd(cursor + d, 1);
  csr_src[pos] = s;
}

// ---------------- fused 2-layer LSTM (16 waves/block) ----------------
// 64 nodes/block (lane=node). Wave w: gate q=w>>2, quarter r=w&3 ->
// rows q*64+r*16 .. +15 (wave-uniform -> weights via s_load). acc[16].
__global__ __launch_bounds__(1024, 4) void lstm_fused(
    const float* __restrict__ x,
    const float* __restrict__ W0T, const float* __restrict__ W1T,
    const float* __restrict__ b0,  const float* __restrict__ b1,
    float* __restrict__ h1out)
{
  __shared__ float g_lds[4][16][64];   // 16KB gate exchange (16 units/chunk)
  __shared__ float h0_lds[64][64];     // 16KB [unit][node]
  __shared__ float h1_lds[64][64];     // 16KB
  __shared__ float x_lds[32][65];      // 8.3KB [k][node], padded

  const int tid  = threadIdx.x;
  const int lane = tid & 63;
  const int wv   = __builtin_amdgcn_readfirstlane(tid >> 6);  // 0..15
  const int q    = wv >> 2;
  const int r    = wv & 3;
  const int row0 = q*64 + r*16;
  const int gbase = blockIdx.x * 64;

  float c0[4], c1[4];
#pragma unroll
  for (int i=0;i<4;i++){ c0[i]=0.f; c1[i]=0.f; }
  for (int i=tid;i<64*64;i+=1024){ ((float*)h0_lds)[i]=0.f; ((float*)h1_lds)[i]=0.f; }

  const float* W0 = W0T + row0;
  const float* W1 = W1T + row0;

  // x staging mapping: thread loads (k = tid&31) for nodes (tid>>5) and (tid>>5)+32
  const int skk = tid & 31, snd = tid >> 5;   // snd 0..31
  const int sn1 = gbase + snd, sn2 = gbase + snd + 32;
  const size_t sb1 = (size_t)((sn1 < NN) ? sn1 : NN-1)*(TT*INF_) + skk;
  const size_t sb2 = (size_t)((sn2 < NN) ? sn2 : NN-1)*(TT*INF_) + skk;

  for (int t=0; t<TT; ++t){
    // must also cover initial h-zero visibility (t=0) via this barrier pair
    __syncthreads();
    x_lds[skk][snd]      = x[sb1 + t*INF_];
    x_lds[skk][snd + 32] = x[sb2 + t*INF_];
    __syncthreads();

    // ---- layer 0: rows row0..row0+15 ----
    float acc[16];
#pragma unroll
    for (int j=0;j<16;j++) acc[j] = b0[row0 + j];
#pragma unroll 4
    for (int k=0;k<INF_;k++){
      const float hv = x_lds[k][lane];
      const float* wk = W0 + k*256;
#pragma unroll
      for (int j=0;j<16;j++) acc[j] = fmaf(wk[j], hv, acc[j]);
    }
#pragma unroll 4
    for (int k=0;k<HID;k++){
      const float hv = h0_lds[k][lane];
      const float* wk = W0 + (INF_+k)*256;
#pragma unroll
      for (int j=0;j<16;j++) acc[j] = fmaf(wk[j], hv, acc[j]);
    }
#pragma unroll
    for (int ch=0; ch<4; ++ch){
      __syncthreads();
      if (r == ch){
#pragma unroll
        for (int j=0;j<16;j++) g_lds[q][j][lane] = acc[j];
      }
      __syncthreads();
      const float gi = g_lds[0][wv][lane];
      const float gf = g_lds[1][wv][lane];
      const float gg = g_lds[2][wv][lane];
      const float go = g_lds[3][wv][lane];
      const float cc = sigf(gf)*c0[ch] + sigf(gi)*tanhf_(gg);
      c0[ch] = cc;
      h0_lds[ch*16 + wv][lane] = sigf(go)*tanhf_(cc);
    }
    __syncthreads();

    // ---- layer 1 ----
#pragma unroll
    for (int j=0;j<16;j++) acc[j] = b1[row0 + j];
#pragma unroll 4
    for (int k=0;k<HID;k++){
      const float hv = h0_lds[k][lane];
      const float* wk = W1 + k*256;
#pragma unroll
      for (int j=0;j<16;j++) acc[j] = fmaf(wk[j], hv, acc[j]);
    }
#pragma unroll 4
    for (int k=0;k<HID;k++){
      const float hv = h1_lds[k][lane];
      const float* wk = W1 + (HID+k)*256;
#pragma unroll
      for (int j=0;j<16;j++) acc[j] = fmaf(wk[j], hv, acc[j]);
    }
#pragma unroll
    for (int ch=0; ch<4; ++ch){
      __syncthreads();
      if (r == ch){
#pragma unroll
        for (int j=0;j<16;j++) g_lds[q][j][lane] = acc[j];
      }
      __syncthreads();
      const float gi = g_lds[0][wv][lane];
      const float gf = g_lds[1][wv][lane];
      const float gg = g_lds[2][wv][lane];
      const float go = g_lds[3][wv][lane];
      const float cc = sigf(gf)*c1[ch] + sigf(gi)*tanhf_(gg);
      c1[ch] = cc;
      h1_lds[ch*16 + wv][lane] = sigf(go)*tanhf_(cc);
    }
  }
  __syncthreads();
  for (int i=tid;i<64*64;i+=1024){
    const int nn = i>>6, u = i&63;
    if (gbase+nn < NN) h1out[(size_t)(gbase+nn)*64 + u] = h1_lds[u][nn];
  }
}

// ---------------- GAT layer 1 prep ----------------
__global__ __launch_bounds__(256) void gat1_prep(const float* __restrict__ h1, const float* __restrict__ W,
  const float* __restrict__ as_, const float* __restrict__ ad_,
  float* __restrict__ xh, float* __restrict__ als, float* __restrict__ ald)
{
  const int nb = blockIdx.x;
  const int o  = threadIdx.x;
  const int q  = o >> 6, u = o & 63;
  const float* hp = h1 + (size_t)nb*64;
  float acc = 0.f;
#pragma unroll 8
  for (int k=0;k<64;k++) acc = fmaf(hp[k], W[k*256 + o], acc);
  xh[(size_t)nb*256 + o] = acc;
  float ps = acc * as_[o];
  float pd = acc * ad_[o];
#pragma unroll
  for (int off=32; off>=1; off>>=1){ ps += __shfl_xor(ps, off); pd += __shfl_xor(pd, off); }
  if (u == 0){ als[nb*4 + q] = ps; ald[nb*4 + q] = pd; }
}

// ---------------- GAT1 gather + fused epilogue ----------------
__global__ __launch_bounds__(256) void gat1_gather(
  const int* __restrict__ indptr, const int* __restrict__ csr_src,
  const float* __restrict__ als, const float* __restrict__ ald,
  const float* __restrict__ xh,  const float* __restrict__ b1g,
  const float* __restrict__ w2,  const float* __restrict__ as2, const float* __restrict__ ad2,
  float* __restrict__ xh2, float* __restrict__ a2s, float* __restrict__ a2d)
{
  const int d = blockIdx.x*4 + (threadIdx.x >> 6);
  const int lane = threadIdx.x & 63;
  if (d >= NN) return;
  const int p0 = indptr[d], p1 = indptr[d+1];

  float aldv[4];
#pragma unroll
  for (int q=0;q<4;q++) aldv[q] = ald[d*4+q];

  float mx[4];
#pragma unroll
  for (int q=0;q<4;q++) mx[q] = -3.4e38f;
  for (int e=p0+lane; e<p1; e+=64){
    int s = csr_src[e];
#pragma unroll
    for (int q=0;q<4;q++){
      float ev = lrelu(als[s*4+q] + aldv[q]);
      mx[q] = fmaxf(mx[q], ev);
    }
  }
#pragma unroll
  for (int off=32; off>=1; off>>=1){
#pragma unroll
    for (int q=0;q<4;q++) mx[q] = fmaxf(mx[q], __shfl_xor(mx[q], off));
  }

  const int q = lane >> 4;
  const float mq = mx[q];
  const float aldq = aldv[q];
  float ax=0.f, ay=0.f, az=0.f, aw=0.f, den=0.f;
  int s_next = (p0 < p1) ? csr_src[p0] : 0;
  for (int e=p0; e<p1; ++e){
    const int s = s_next;
    if (e+1 < p1) s_next = csr_src[e+1];
    float ev = lrelu(als[s*4+q] + aldq);
    float ex = __expf(ev - mq);
    den += ex;
    float4 v = *(const float4*)(xh + (size_t)s*256 + lane*4);
    ax = fmaf(ex, v.x, ax); ay = fmaf(ex, v.y, ay);
    az = fmaf(ex, v.z, az); aw = fmaf(ex, v.w, aw);
  }
  const float rr = 1.0f/(den + 1e-16f);
  const int o = lane*4;
  float v0 = ax*rr + b1g[o+0];
  float v1 = ay*rr + b1g[o+1];
  float v2 = az*rr + b1g[o+2];
  float v3 = aw*rr + b1g[o+3];
  v0 = v0>0.f?v0:0.f; v1 = v1>0.f?v1:0.f; v2 = v2>0.f?v2:0.f; v3 = v3>0.f?v3:0.f;
  float part = v0*w2[o+0] + v1*w2[o+1] + v2*w2[o+2] + v3*w2[o+3];
#pragma unroll
  for (int off=32; off>=1; off>>=1) part += __shfl_xor(part, off);
  if (lane == 0){
    xh2[d] = part;
    a2s[d] = part * as2[0];
    a2d[d] = part * ad2[0];
  }
}

// ---------------- GAT2 gather ----------------
__global__ __launch_bounds__(256) void gat2_gather(
  const int* __restrict__ indptr, const int* __restrict__ csr_src,
  const float* __restrict__ a2s, const float* __restrict__ a2d,
  const float* __restrict__ xh2, const float* __restrict__ b2,
  float* __restrict__ out)
{
  const int d = blockIdx.x*4 + (threadIdx.x >> 6);
  const int lane = threadIdx.x & 63;
  if (d >= NN) return;
  const int p0 = indptr[d], p1 = indptr[d+1];
  const float add = a2d[d];

  float mx = -3.4e38f;
  for (int e=p0+lane; e<p1; e+=64){
    int s = csr_src[e];
    mx = fmaxf(mx, lrelu(a2s[s] + add));
  }
#pragma unroll
  for (int off=32; off>=1; off>>=1) mx = fmaxf(mx, __shfl_xor(mx, off));

  float den = 0.f, num = 0.f;
  for (int e=p0+lane; e<p1; e+=64){
    int s = csr_src[e];
    float ev = lrelu(a2s[s] + add);
    float ex = __expf(ev - mx);
    den += ex;
    num = fmaf(ex, xh2[s], num);
  }
#pragma unroll
  for (int off=32; off>=1; off>>=1){ den += __shfl_xor(den, off); num += __shfl_xor(num, off); }
  if (lane == 0) out[d] = num/(den + 1e-16f) + b2[0];
}

// ---------------- launcher ----------------
extern "C" void kernel_launch(void* const* d_in, const int* in_sizes, int n_in,
                              void* d_out, int out_size, void* d_ws, size_t ws_size,
                              hipStream_t stream)
{
  const float* x    = (const float*)d_in[0];
  const int*   ei   = (const int*)d_in[1];
  const float* Wih0 = (const float*)d_in[2];
  const float* Whh0 = (const float*)d_in[3];
  const float* bih0 = (const float*)d_in[4];
  const float* bhh0 = (const float*)d_in[5];
  const float* Wih1 = (const float*)d_in[6];
  const float* Whh1 = (const float*)d_in[7];
  const float* bih1 = (const float*)d_in[8];
  const float* bhh1 = (const float*)d_in[9];
  const float* g1w  = (const float*)d_in[10];
  const float* g1as = (const float*)d_in[11];
  const float* g1ad = (const float*)d_in[12];
  const float* g1b  = (const float*)d_in[13];
  const float* g2w  = (const float*)d_in[14];
  const float* g2as = (const float*)d_in[15];
  const float* g2ad = (const float*)d_in[16];
  const float* g2b  = (const float*)d_in[17];

  float* ws  = (float*)d_ws;
  float* W0T = ws;                    // 96*256
  float* W1T = W0T + 96*256;          // 128*256
  float* b0  = W1T + 128*256;         // 256
  float* b1  = b0 + 256;              // 256
  float* h1  = b1 + 256;              // 20000*64
  float* xh  = h1 + 1280000;          // 20000*256
  float* als = xh + 5120000;          // 80000
  float* ald = als + 80000;           // 80000
  float* xh2 = ald + 80000;           // 20000
  float* a2s = xh2 + 20000;           // 20000
  float* a2d = a2s + 20000;           // 20000
  int*   deg    = (int*)(a2d + 20000);   // 20000
  int*   indptr = deg + 20000;           // 20001
  int*   cursor = indptr + 20001;        // 20000
  int*   csr    = cursor + 20000;        // 340000

  kzero_int<<<(NN+255)/256, 256, 0, stream>>>(deg, NN);
  pack_weights<<<226, 256, 0, stream>>>(Wih0,Whh0,bih0,bhh0,Wih1,Whh1,bih1,bhh1,W0T,W1T,b0,b1);
  count_deg<<<(ETOT+255)/256, 256, 0, stream>>>(ei, deg);
  scan_deg<<<1, 256, 0, stream>>>(deg, indptr, cursor);
  scatter_edges<<<(ETOT+255)/256, 256, 0, stream>>>(ei, cursor, csr);
  lstm_fused<<<313, 1024, 0, stream>>>(x, W0T, W1T, b0, b1, h1);
  gat1_prep<<<NN, 256, 0, stream>>>(h1, g1w, g1as, g1ad, xh, als, ald);
  gat1_gather<<<(NN+3)/4, 256, 0, stream>>>(indptr, csr, als, ald, xh, g1b, g2w, g2as, g2ad, xh2, a2s, a2d);
  gat2_gather<<<(NN+3)/4, 256, 0, stream>>>(indptr, csr, a2s, a2d, xh2, g2b, (float*)d_out);
}

// Round 4
// 876.736 us; speedup vs baseline: 8.9914x; 2.2935x over previous
//
#include <hip/hip_runtime.h>
#include <math.h>

#define NN   20000
#define TT   32
#define INF_ 32
#define HID  64
#define NH   4
#define EE   320000
#define ETOT (EE + NN)
#define ZROW 164   // bf16 elems per Z row: 160 data + 4 pad (stride 82 dw -> conflict-free frags)

typedef __attribute__((ext_vector_type(8))) short bf16x8;
typedef __attribute__((ext_vector_type(4))) short short4v;
typedef __attribute__((ext_vector_type(4))) float f32x4;

static __device__ __forceinline__ float sigf(float x){ return 1.0f/(1.0f+__expf(-x)); }
static __device__ __forceinline__ float tanhf_(float x){ float e=__expf(2.0f*x); return 1.0f - 2.0f/(e+1.0f); }
static __device__ __forceinline__ float lrelu(float x){ return x>0.0f ? x : 0.2f*x; }

static __device__ __forceinline__ unsigned short f2bf(float f){
  unsigned u = __float_as_uint(f);
  unsigned r = u + 0x7fffu + ((u>>16)&1u);
  return (unsigned short)(r>>16);
}
static __device__ __forceinline__ float bf2f(unsigned short h){ return __uint_as_float(((unsigned)h)<<16); }

static __device__ __forceinline__ void edge_sd(const int* __restrict__ ei, int e, int& s, int& d){
  if (e < EE){ s = ei[e]; d = ei[EE + e]; } else { s = e - EE; d = s; }
}

// ---------------- utility kernels ----------------
__global__ void kzero_int(int* __restrict__ p, int n){
  int i = blockIdx.x*256 + threadIdx.x;
  if (i < n) p[i] = 0;
}

// Pack weights into MFMA A-fragment layout (split bf16 hi/lo) + bias sums.
// L0 frag-lane idx = ((w*3+ks)*2+h)*64 + l ; L1 base 6144 frag-lanes.
// elem j of lane l: k = ks*32 + 4*(l>>4) + (j&3) + 16*(j>>2); gate = w*16 + (l&15)
__global__ void pack_weights(const float* __restrict__ Wih0, const float* __restrict__ Whh0,
                             const float* __restrict__ bih0, const float* __restrict__ bhh0,
                             const float* __restrict__ Wih1, const float* __restrict__ Whh1,
                             const float* __restrict__ bih1, const float* __restrict__ bhh1,
                             unsigned short* __restrict__ Wpk,
                             float* __restrict__ b0, float* __restrict__ b1){
  int idx = blockIdx.x*256 + threadIdx.x;
  if (idx < 49152){
    int fb = idx >> 9;          // 0..95
    int h  = fb & 1;
    int t2 = fb >> 1;           // 0..47
    int ks = t2 % 3, w = t2 / 3;
    int r  = idx & 511;
    int l  = r >> 3, j = r & 7;
    int gate = w*16 + (l & 15);
    int k = ks*32 + 4*(l>>4) + (j & 3) + 16*(j >> 2);
    float src = (k < 32) ? Wih0[gate*32 + k] : Whh0[gate*64 + (k - 32)];
    unsigned short hi = f2bf(src);
    Wpk[idx] = h ? f2bf(src - bf2f(hi)) : hi;
  } else if (idx < 114688){
    int idx2 = idx - 49152;
    int fb = idx2 >> 9;         // 0..127
    int h  = fb & 1;
    int t2 = fb >> 1;           // 0..63
    int ks = t2 & 3, w = t2 >> 2;
    int r  = idx2 & 511;
    int l  = r >> 3, j = r & 7;
    int gate = w*16 + (l & 15);
    int k = ks*32 + 4*(l>>4) + (j & 3) + 16*(j >> 2);   // 0..127
    float src = (k < 64) ? Wih1[gate*64 + k] : Whh1[gate*64 + (k - 64)];
    unsigned short hi = f2bf(src);
    Wpk[idx] = h ? f2bf(src - bf2f(hi)) : hi;
  } else {
    int m = idx - 114688;
    if (m < 256) b0[m] = bih0[m] + bhh0[m];
    else if (m < 512) b1[m-256] = bih1[m-256] + bhh1[m-256];
  }
}

// ---------------- CSR build (dst-indexed) ----------------
__global__ void count_deg(const int* __restrict__ ei, int* __restrict__ deg){
  int e = blockIdx.x*256 + threadIdx.x;
  if (e >= ETOT) return;
  int s, d; edge_sd(ei, e, s, d);
  atomicAdd(deg + d, 1);
}

__global__ void scan_deg(const int* __restrict__ deg, int* __restrict__ indptr, int* __restrict__ cursor){
  __shared__ int part[256];
  const int t = threadIdx.x;
  const int CH = (NN + 255) / 256;
  const int c0 = t * CH;
  int sum = 0;
  for (int i=0;i<CH;i++){ int idx=c0+i; if (idx<NN) sum += deg[idx]; }
  part[t] = sum; __syncthreads();
  int val = sum;
  for (int off=1; off<256; off<<=1){
    int add = (t>=off) ? part[t-off] : 0;
    __syncthreads();
    val += add; part[t] = val;
    __syncthreads();
  }
  int run = val - sum;
  for (int i=0;i<CH;i++){
    int idx=c0+i;
    if (idx<NN){ indptr[idx]=run; cursor[idx]=run; run += deg[idx]; }
  }
  if (t == 0) indptr[NN] = ETOT;
}

__global__ void scatter_edges(const int* __restrict__ ei, int* __restrict__ cursor, int* __restrict__ csr_src){
  int e = blockIdx.x*256 + threadIdx.x;
  if (e >= ETOT) return;
  int s, d; edge_sd(ei, e, s, d);
  int pos = atomicAdd(cursor + d, 1);
  csr_src[pos] = s;
}

// ---------------- MFMA split-bf16 2-layer LSTM ----------------
// 64 nodes/block, 1024 thr = 16 waves. Wave w owns gates w*16..w*16+15 (A-side);
// weights held in VGPRs (packed frags). Z = [x(0..31) | h0(32..95) | h1(96..159)]
// as bf16 hi/lo in LDS [64][ZROW]. G exchange f32. c-state in registers.
__global__ __launch_bounds__(1024, 4) void lstm_mfma(
    const float* __restrict__ x,
    const unsigned short* __restrict__ Wpk,
    const float* __restrict__ b0, const float* __restrict__ b1,
    float* __restrict__ h1out)
{
  __shared__ unsigned short Zh[64*ZROW];
  __shared__ unsigned short Zl[64*ZROW];
  __shared__ float G[4][64][68];

  const int tid  = threadIdx.x;
  const int lane = tid & 63;
  const int w    = __builtin_amdgcn_readfirstlane(tid >> 6);   // 0..15
  const int ln15 = lane & 15;
  const int lq   = lane >> 4;                                  // 0..3
  const int gbase = blockIdx.x * 64;

  // ---- load weight fragments into registers (held across all t) ----
  const bf16x8* wp = (const bf16x8*)Wpk;
  bf16x8 wA0h[3], wA0l[3], wA1h[4], wA1l[4];
#pragma unroll
  for (int ks=0; ks<3; ++ks){
    wA0h[ks] = wp[((w*3 + ks)*2 + 0)*64 + lane];
    wA0l[ks] = wp[((w*3 + ks)*2 + 1)*64 + lane];
  }
#pragma unroll
  for (int ks=0; ks<4; ++ks){
    wA1h[ks] = wp[6144 + ((w*4 + ks)*2 + 0)*64 + lane];
    wA1l[ks] = wp[6144 + ((w*4 + ks)*2 + 1)*64 + lane];
  }
  // bias for this lane's C rows: gate = w*16 + lq*4 + r
  float bv0[4], bv1[4];
#pragma unroll
  for (int r=0; r<4; ++r){
    bv0[r] = b0[w*16 + lq*4 + r];
    bv1[r] = b1[w*16 + lq*4 + r];
  }

  // zero h regions (and everything) in Z
  for (int i = tid; i < 64*ZROW; i += 1024){ Zh[i] = 0; Zl[i] = 0; }

  float c0[4], c1[4];
#pragma unroll
  for (int i=0;i<4;i++){ c0[i]=0.f; c1[i]=0.f; }

  // x staging: thread covers node sn_=tid>>4, k-pair sk=(tid&15)*2
  const int sn_ = tid >> 4;            // 0..63
  const int sk  = (tid & 15) * 2;      // 0..30
  const int sgn = gbase + sn_;
  const float* xp = x + (size_t)((sgn < NN) ? sgn : NN-1)*(TT*INF_) + sk;

  const int u0 = w << 2;               // pointwise units u0..u0+3, node = lane

#define ZFRAG(Zb, node, kz) ({                                            \
    const unsigned short* _p = &Zb[(node)*ZROW + (kz) + 4*lq];            \
    short4v _a = *(const short4v*)_p;                                     \
    short4v _b = *(const short4v*)(_p + 16);                              \
    __builtin_shufflevector(_a, _b, 0,1,2,3,4,5,6,7); })

  for (int t=0; t<TT; ++t){
    __syncthreads();
    // ---- stage x_t (bf16 hi/lo pairs) ----
    {
      const float2 xv = *(const float2*)(xp + t*INF_);
      unsigned short ha = f2bf(xv.x), hb = f2bf(xv.y);
      unsigned short la = f2bf(xv.x - bf2f(ha)), lb = f2bf(xv.y - bf2f(hb));
      *(unsigned*)&Zh[sn_*ZROW + sk] = (unsigned)ha | ((unsigned)hb << 16);
      *(unsigned*)&Zl[sn_*ZROW + sk] = (unsigned)la | ((unsigned)lb << 16);
    }
    __syncthreads();

    // ---- L0 MFMA: G0 = W0 * Z[0..95] ----
    {
      f32x4 acc0, acc1, acc2, acc3;
      acc0 = acc1 = acc2 = acc3 = (f32x4){bv0[0], bv0[1], bv0[2], bv0[3]};
#pragma unroll
      for (int ks=0; ks<3; ++ks){
        const int kz = ks*32;
        const bf16x8 wh = wA0h[ks], wl = wA0l[ks];
        bf16x8 zh, zl;
        zh = ZFRAG(Zh, ln15,      kz); zl = ZFRAG(Zl, ln15,      kz);
        acc0 = __builtin_amdgcn_mfma_f32_16x16x32_bf16(wh, zh, acc0, 0,0,0);
        acc0 = __builtin_amdgcn_mfma_f32_16x16x32_bf16(wh, zl, acc0, 0,0,0);
        acc0 = __builtin_amdgcn_mfma_f32_16x16x32_bf16(wl, zh, acc0, 0,0,0);
        zh = ZFRAG(Zh, 16+ln15,   kz); zl = ZFRAG(Zl, 16+ln15,   kz);
        acc1 = __builtin_amdgcn_mfma_f32_16x16x32_bf16(wh, zh, acc1, 0,0,0);
        acc1 = __builtin_amdgcn_mfma_f32_16x16x32_bf16(wh, zl, acc1, 0,0,0);
        acc1 = __builtin_amdgcn_mfma_f32_16x16x32_bf16(wl, zh, acc1, 0,0,0);
        zh = ZFRAG(Zh, 32+ln15,   kz); zl = ZFRAG(Zl, 32+ln15,   kz);
        acc2 = __builtin_amdgcn_mfma_f32_16x16x32_bf16(wh, zh, acc2, 0,0,0);
        acc2 = __builtin_amdgcn_mfma_f32_16x16x32_bf16(wh, zl, acc2, 0,0,0);
        acc2 = __builtin_amdgcn_mfma_f32_16x16x32_bf16(wl, zh, acc2, 0,0,0);
        zh = ZFRAG(Zh, 48+ln15,   kz); zl = ZFRAG(Zl, 48+ln15,   kz);
        acc3 = __builtin_amdgcn_mfma_f32_16x16x32_bf16(wh, zh, acc3, 0,0,0);
        acc3 = __builtin_amdgcn_mfma_f32_16x16x32_bf16(wh, zl, acc3, 0,0,0);
        acc3 = __builtin_amdgcn_mfma_f32_16x16x32_bf16(wl, zh, acc3, 0,0,0);
      }
      // write G0: wave w -> gate type qg=w>>2, units sub*16 + lq*4 + r
      const int qg = w >> 2, ub = (w & 3)*16 + lq*4;
#pragma unroll
      for (int r=0; r<4; ++r){
        G[qg][ub+r][ 0+ln15] = acc0[r];
        G[qg][ub+r][16+ln15] = acc1[r];
        G[qg][ub+r][32+ln15] = acc2[r];
        G[qg][ub+r][48+ln15] = acc3[r];
      }
    }
    __syncthreads();

    // ---- pointwise L0: h0 -> Z[32..95] ----
    {
      float hh[4];
#pragma unroll
      for (int j=0; j<4; ++j){
        const int u = u0 + j;
        float gi = G[0][u][lane], gf = G[1][u][lane], gg = G[2][u][lane], go = G[3][u][lane];
        float cc = sigf(gf)*c0[j] + sigf(gi)*tanhf_(gg);
        c0[j] = cc;
        hh[j] = sigf(go)*tanhf_(cc);
      }
      unsigned short h0_ = f2bf(hh[0]), h1_ = f2bf(hh[1]), h2_ = f2bf(hh[2]), h3_ = f2bf(hh[3]);
      unsigned short l0_ = f2bf(hh[0]-bf2f(h0_)), l1_ = f2bf(hh[1]-bf2f(h1_));
      unsigned short l2_ = f2bf(hh[2]-bf2f(h2_)), l3_ = f2bf(hh[3]-bf2f(h3_));
      unsigned* zh32 = (unsigned*)&Zh[lane*ZROW + 32 + u0];
      unsigned* zl32 = (unsigned*)&Zl[lane*ZROW + 32 + u0];
      zh32[0] = (unsigned)h0_ | ((unsigned)h1_<<16); zh32[1] = (unsigned)h2_ | ((unsigned)h3_<<16);
      zl32[0] = (unsigned)l0_ | ((unsigned)l1_<<16); zl32[1] = (unsigned)l2_ | ((unsigned)l3_<<16);
    }
    __syncthreads();

    // ---- L1 MFMA: G1 = W1 * Z[32..159] ----
    {
      f32x4 acc0, acc1, acc2, acc3;
      acc0 = acc1 = acc2 = acc3 = (f32x4){bv1[0], bv1[1], bv1[2], bv1[3]};
#pragma unroll
      for (int ks=0; ks<4; ++ks){
        const int kz = 32 + ks*32;
        const bf16x8 wh = wA1h[ks], wl = wA1l[ks];
        bf16x8 zh, zl;
        zh = ZFRAG(Zh, ln15,      kz); zl = ZFRAG(Zl, ln15,      kz);
        acc0 = __builtin_amdgcn_mfma_f32_16x16x32_bf16(wh, zh, acc0, 0,0,0);
        acc0 = __builtin_amdgcn_mfma_f32_16x16x32_bf16(wh, zl, acc0, 0,0,0);
        acc0 = __builtin_amdgcn_mfma_f32_16x16x32_bf16(wl, zh, acc0, 0,0,0);
        zh = ZFRAG(Zh, 16+ln15,   kz); zl = ZFRAG(Zl, 16+ln15,   kz);
        acc1 = __builtin_amdgcn_mfma_f32_16x16x32_bf16(wh, zh, acc1, 0,0,0);
        acc1 = __builtin_amdgcn_mfma_f32_16x16x32_bf16(wh, zl, acc1, 0,0,0);
        acc1 = __builtin_amdgcn_mfma_f32_16x16x32_bf16(wl, zh, acc1, 0,0,0);
        zh = ZFRAG(Zh, 32+ln15,   kz); zl = ZFRAG(Zl, 32+ln15,   kz);
        acc2 = __builtin_amdgcn_mfma_f32_16x16x32_bf16(wh, zh, acc2, 0,0,0);
        acc2 = __builtin_amdgcn_mfma_f32_16x16x32_bf16(wh, zl, acc2, 0,0,0);
        acc2 = __builtin_amdgcn_mfma_f32_16x16x32_bf16(wl, zh, acc2, 0,0,0);
        zh = ZFRAG(Zh, 48+ln15,   kz); zl = ZFRAG(Zl, 48+ln15,   kz);
        acc3 = __builtin_amdgcn_mfma_f32_16x16x32_bf16(wh, zh, acc3, 0,0,0);
        acc3 = __builtin_amdgcn_mfma_f32_16x16x32_bf16(wh, zl, acc3, 0,0,0);
        acc3 = __builtin_amdgcn_mfma_f32_16x16x32_bf16(wl, zh, acc3, 0,0,0);
      }
      const int qg = w >> 2, ub = (w & 3)*16 + lq*4;
#pragma unroll
      for (int r=0; r<4; ++r){
        G[qg][ub+r][ 0+ln15] = acc0[r];
        G[qg][ub+r][16+ln15] = acc1[r];
        G[qg][ub+r][32+ln15] = acc2[r];
        G[qg][ub+r][48+ln15] = acc3[r];
      }
    }
    __syncthreads();

    // ---- pointwise L1: h1 -> Z[96..159] ----
    {
      float hh[4];
#pragma unroll
      for (int j=0; j<4; ++j){
        const int u = u0 + j;
        float gi = G[0][u][lane], gf = G[1][u][lane], gg = G[2][u][lane], go = G[3][u][lane];
        float cc = sigf(gf)*c1[j] + sigf(gi)*tanhf_(gg);
        c1[j] = cc;
        hh[j] = sigf(go)*tanhf_(cc);
      }
      unsigned short h0_ = f2bf(hh[0]), h1_ = f2bf(hh[1]), h2_ = f2bf(hh[2]), h3_ = f2bf(hh[3]);
      unsigned short l0_ = f2bf(hh[0]-bf2f(h0_)), l1_ = f2bf(hh[1]-bf2f(h1_));
      unsigned short l2_ = f2bf(hh[2]-bf2f(h2_)), l3_ = f2bf(hh[3]-bf2f(h3_));
      unsigned* zh32 = (unsigned*)&Zh[lane*ZROW + 96 + u0];
      unsigned* zl32 = (unsigned*)&Zl[lane*ZROW + 96 + u0];
      zh32[0] = (unsigned)h0_ | ((unsigned)h1_<<16); zh32[1] = (unsigned)h2_ | ((unsigned)h3_<<16);
      zl32[0] = (unsigned)l0_ | ((unsigned)l1_<<16); zl32[1] = (unsigned)l2_ | ((unsigned)l3_<<16);
    }
  }
  __syncthreads();
  // ---- write h1 (last t) from Z[96..159] ----
  for (int o = tid; o < 4096; o += 1024){
    const int n = o >> 6, u = o & 63;
    if (gbase + n < NN){
      float h = bf2f(Zh[n*ZROW + 96 + u]) + bf2f(Zl[n*ZROW + 96 + u]);
      h1out[(size_t)(gbase+n)*64 + u] = h;
    }
  }
#undef ZFRAG
}

// ---------------- GAT layer 1 prep ----------------
__global__ __launch_bounds__(256) void gat1_prep(const float* __restrict__ h1, const float* __restrict__ W,
  const float* __restrict__ as_, const float* __restrict__ ad_,
  float* __restrict__ xh, float* __restrict__ als, float* __restrict__ ald)
{
  const int nb = blockIdx.x;
  const int o  = threadIdx.x;
  const int q  = o >> 6, u = o & 63;
  const float* hp = h1 + (size_t)nb*64;
  float acc = 0.f;
#pragma unroll 8
  for (int k=0;k<64;k++) acc = fmaf(hp[k], W[k*256 + o], acc);
  xh[(size_t)nb*256 + o] = acc;
  float ps = acc * as_[o];
  float pd = acc * ad_[o];
#pragma unroll
  for (int off=32; off>=1; off>>=1){ ps += __shfl_xor(ps, off); pd += __shfl_xor(pd, off); }
  if (u == 0){ als[nb*4 + q] = ps; ald[nb*4 + q] = pd; }
}

// ---------------- GAT1 gather + fused epilogue ----------------
__global__ __launch_bounds__(256) void gat1_gather(
  const int* __restrict__ indptr, const int* __restrict__ csr_src,
  const float* __restrict__ als, const float* __restrict__ ald,
  const float* __restrict__ xh,  const float* __restrict__ b1g,
  const float* __restrict__ w2,  const float* __restrict__ as2, const float* __restrict__ ad2,
  float* __restrict__ xh2, float* __restrict__ a2s, float* __restrict__ a2d)
{
  const int d = blockIdx.x*4 + (threadIdx.x >> 6);
  const int lane = threadIdx.x & 63;
  if (d >= NN) return;
  const int p0 = indptr[d], p1 = indptr[d+1];

  float aldv[4];
#pragma unroll
  for (int q=0;q<4;q++) aldv[q] = ald[d*4+q];

  float mx[4];
#pragma unroll
  for (int q=0;q<4;q++) mx[q] = -3.4e38f;
  for (int e=p0+lane; e<p1; e+=64){
    int s = csr_src[e];
#pragma unroll
    for (int q=0;q<4;q++){
      float ev = lrelu(als[s*4+q] + aldv[q]);
      mx[q] = fmaxf(mx[q], ev);
    }
  }
#pragma unroll
  for (int off=32; off>=1; off>>=1){
#pragma unroll
    for (int q=0;q<4;q++) mx[q] = fmaxf(mx[q], __shfl_xor(mx[q], off));
  }

  const int q = lane >> 4;
  const float mq = mx[q];
  const float aldq = aldv[q];
  float ax=0.f, ay=0.f, az=0.f, aw=0.f, den=0.f;
  int s_next = (p0 < p1) ? csr_src[p0] : 0;
  for (int e=p0; e<p1; ++e){
    const int s = s_next;
    if (e+1 < p1) s_next = csr_src[e+1];
    float ev = lrelu(als[s*4+q] + aldq);
    float ex = __expf(ev - mq);
    den += ex;
    float4 v = *(const float4*)(xh + (size_t)s*256 + lane*4);
    ax = fmaf(ex, v.x, ax); ay = fmaf(ex, v.y, ay);
    az = fmaf(ex, v.z, az); aw = fmaf(ex, v.w, aw);
  }
  const float rr = 1.0f/(den + 1e-16f);
  const int o = lane*4;
  float v0 = ax*rr + b1g[o+0];
  float v1 = ay*rr + b1g[o+1];
  float v2 = az*rr + b1g[o+2];
  float v3 = aw*rr + b1g[o+3];
  v0 = v0>0.f?v0:0.f; v1 = v1>0.f?v1:0.f; v2 = v2>0.f?v2:0.f; v3 = v3>0.f?v3:0.f;
  float part = v0*w2[o+0] + v1*w2[o+1] + v2*w2[o+2] + v3*w2[o+3];
#pragma unroll
  for (int off=32; off>=1; off>>=1) part += __shfl_xor(part, off);
  if (lane == 0){
    xh2[d] = part;
    a2s[d] = part * as2[0];
    a2d[d] = part * ad2[0];
  }
}

// ---------------- GAT2 gather ----------------
__global__ __launch_bounds__(256) void gat2_gather(
  const int* __restrict__ indptr, const int* __restrict__ csr_src,
  const float* __restrict__ a2s, const float* __restrict__ a2d,
  const float* __restrict__ xh2, const float* __restrict__ b2,
  float* __restrict__ out)
{
  const int d = blockIdx.x*4 + (threadIdx.x >> 6);
  const int lane = threadIdx.x & 63;
  if (d >= NN) return;
  const int p0 = indptr[d], p1 = indptr[d+1];
  const float add = a2d[d];

  float mx = -3.4e38f;
  for (int e=p0+lane; e<p1; e+=64){
    int s = csr_src[e];
    mx = fmaxf(mx, lrelu(a2s[s] + add));
  }
#pragma unroll
  for (int off=32; off>=1; off>>=1) mx = fmaxf(mx, __shfl_xor(mx, off));

  float den = 0.f, num = 0.f;
  for (int e=p0+lane; e<p1; e+=64){
    int s = csr_src[e];
    float ev = lrelu(a2s[s] + add);
    float ex = __expf(ev - mx);
    den += ex;
    num = fmaf(ex, xh2[s], num);
  }
#pragma unroll
  for (int off=32; off>=1; off>>=1){ den += __shfl_xor(den, off); num += __shfl_xor(num, off); }
  if (lane == 0) out[d] = num/(den + 1e-16f) + b2[0];
}

// ---------------- launcher ----------------
extern "C" void kernel_launch(void* const* d_in, const int* in_sizes, int n_in,
                              void* d_out, int out_size, void* d_ws, size_t ws_size,
                              hipStream_t stream)
{
  const float* x    = (const float*)d_in[0];
  const int*   ei   = (const int*)d_in[1];
  const float* Wih0 = (const float*)d_in[2];
  const float* Whh0 = (const float*)d_in[3];
  const float* bih0 = (const float*)d_in[4];
  const float* bhh0 = (const float*)d_in[5];
  const float* Wih1 = (const float*)d_in[6];
  const float* Whh1 = (const float*)d_in[7];
  const float* bih1 = (const float*)d_in[8];
  const float* bhh1 = (const float*)d_in[9];
  const float* g1w  = (const float*)d_in[10];
  const float* g1as = (const float*)d_in[11];
  const float* g1ad = (const float*)d_in[12];
  const float* g1b  = (const float*)d_in[13];
  const float* g2w  = (const float*)d_in[14];
  const float* g2as = (const float*)d_in[15];
  const float* g2ad = (const float*)d_in[16];
  const float* g2b  = (const float*)d_in[17];

  float* ws  = (float*)d_ws;
  unsigned short* Wpk = (unsigned short*)ws;   // 114688 shorts = 57344 f32 slots
  float* b0  = ws + 57344;            // 256
  float* b1  = b0 + 256;              // 256
  float* h1  = b1 + 256;              // 20000*64
  float* xh  = h1 + 1280000;          // 20000*256
  float* als = xh + 5120000;          // 80000
  float* ald = als + 80000;           // 80000
  float* xh2 = ald + 80000;           // 20000
  float* a2s = xh2 + 20000;           // 20000
  float* a2d = a2s + 20000;           // 20000
  int*   deg    = (int*)(a2d + 20000);   // 20000
  int*   indptr = deg + 20000;           // 20001
  int*   cursor = indptr + 20001;        // 20000
  int*   csr    = cursor + 20000;        // 340000

  kzero_int<<<(NN+255)/256, 256, 0, stream>>>(deg, NN);
  pack_weights<<<450, 256, 0, stream>>>(Wih0,Whh0,bih0,bhh0,Wih1,Whh1,bih1,bhh1,Wpk,b0,b1);
  count_deg<<<(ETOT+255)/256, 256, 0, stream>>>(ei, deg);
  scan_deg<<<1, 256, 0, stream>>>(deg, indptr, cursor);
  scatter_edges<<<(ETOT+255)/256, 256, 0, stream>>>(ei, cursor, csr);
  lstm_mfma<<<313, 1024, 0, stream>>>(x, Wpk, b0, b1, h1);
  gat1_prep<<<NN, 256, 0, stream>>>(h1, g1w, g1as, g1ad, xh, als, ald);
  gat1_gather<<<(NN+3)/4, 256, 0, stream>>>(indptr, csr, als, ald, xh, g1b, g2w, g2as, g2ad, xh2, a2s, a2d);
  gat2_gather<<<(NN+3)/4, 256, 0, stream>>>(indptr, csr, a2s, a2d, xh2, g2b, (float*)d_out);
}

// Round 5
// 792.366 us; speedup vs baseline: 9.9488x; 1.1065x over previous
//
#include <hip/hip_runtime.h>
#include <math.h>

#define NN   20000
#define TT   32
#define INF_ 32
#define HID  64
#define NH   4
#define EE   320000
#define ETOT (EE + NN)
#define ZROW 164   // bf16 elems per Z row (82 dw, ≡18 mod 32 -> conflict-free frag reads)
#define NB   80    // nodes per LSTM block; 250*80 = 20000 exact
#define GST  68    // G unit-stride (64 + 4 pad)

typedef __attribute__((ext_vector_type(8))) short bf16x8;
typedef __attribute__((ext_vector_type(4))) short short4v;
typedef __attribute__((ext_vector_type(4))) float f32x4;

static __device__ __forceinline__ float sigf(float x){ return 1.0f/(1.0f+__expf(-x)); }
static __device__ __forceinline__ float tanhf_(float x){ float e=__expf(2.0f*x); return 1.0f - 2.0f/(e+1.0f); }
static __device__ __forceinline__ float lrelu(float x){ return x>0.0f ? x : 0.2f*x; }

static __device__ __forceinline__ unsigned short f2bf(float f){
  unsigned u = __float_as_uint(f);
  unsigned r = u + 0x7fffu + ((u>>16)&1u);
  return (unsigned short)(r>>16);
}
static __device__ __forceinline__ float bf2f(unsigned short h){ return __uint_as_float(((unsigned)h)<<16); }

static __device__ __forceinline__ void edge_sd(const int* __restrict__ ei, int e, int& s, int& d){
  if (e < EE){ s = ei[e]; d = ei[EE + e]; } else { s = e - EE; d = s; }
}

// ---------------- utility kernels ----------------
__global__ void kzero_int(int* __restrict__ p, int n){
  int i = blockIdx.x*256 + threadIdx.x;
  if (i < n) p[i] = 0;
}

// Pack weights into MFMA A-fragment layout (split bf16 hi/lo) + bias sums.
// (verified in R3 — unchanged)
__global__ void pack_weights(const float* __restrict__ Wih0, const float* __restrict__ Whh0,
                             const float* __restrict__ bih0, const float* __restrict__ bhh0,
                             const float* __restrict__ Wih1, const float* __restrict__ Whh1,
                             const float* __restrict__ bih1, const float* __restrict__ bhh1,
                             unsigned short* __restrict__ Wpk,
                             float* __restrict__ b0, float* __restrict__ b1){
  int idx = blockIdx.x*256 + threadIdx.x;
  if (idx < 49152){
    int fb = idx >> 9;          // 0..95
    int h  = fb & 1;
    int t2 = fb >> 1;           // 0..47
    int ks = t2 % 3, w = t2 / 3;
    int r  = idx & 511;
    int l  = r >> 3, j = r & 7;
    int gate = w*16 + (l & 15);
    int k = ks*32 + 4*(l>>4) + (j & 3) + 16*(j >> 2);
    float src = (k < 32) ? Wih0[gate*32 + k] : Whh0[gate*64 + (k - 32)];
    unsigned short hi = f2bf(src);
    Wpk[idx] = h ? f2bf(src - bf2f(hi)) : hi;
  } else if (idx < 114688){
    int idx2 = idx - 49152;
    int fb = idx2 >> 9;         // 0..127
    int h  = fb & 1;
    int t2 = fb >> 1;           // 0..63
    int ks = t2 & 3, w = t2 >> 2;
    int r  = idx2 & 511;
    int l  = r >> 3, j = r & 7;
    int gate = w*16 + (l & 15);
    int k = ks*32 + 4*(l>>4) + (j & 3) + 16*(j >> 2);   // 0..127
    float src = (k < 64) ? Wih1[gate*64 + k] : Whh1[gate*64 + (k - 64)];
    unsigned short hi = f2bf(src);
    Wpk[idx] = h ? f2bf(src - bf2f(hi)) : hi;
  } else {
    int m = idx - 114688;
    if (m < 256) b0[m] = bih0[m] + bhh0[m];
    else if (m < 512) b1[m-256] = bih1[m-256] + bhh1[m-256];
  }
}

// ---------------- CSR build (dst-indexed) ----------------
__global__ void count_deg(const int* __restrict__ ei, int* __restrict__ deg){
  int e = blockIdx.x*256 + threadIdx.x;
  if (e >= ETOT) return;
  int s, d; edge_sd(ei, e, s, d);
  atomicAdd(deg + d, 1);
}

__global__ void scan_deg(const int* __restrict__ deg, int* __restrict__ indptr, int* __restrict__ cursor){
  __shared__ int part[256];
  const int t = threadIdx.x;
  const int CH = (NN + 255) / 256;
  const int c0 = t * CH;
  int sum = 0;
  for (int i=0;i<CH;i++){ int idx=c0+i; if (idx<NN) sum += deg[idx]; }
  part[t] = sum; __syncthreads();
  int val = sum;
  for (int off=1; off<256; off<<=1){
    int add = (t>=off) ? part[t-off] : 0;
    __syncthreads();
    val += add; part[t] = val;
    __syncthreads();
  }
  int run = val - sum;
  for (int i=0;i<CH;i++){
    int idx=c0+i;
    if (idx<NN){ indptr[idx]=run; cursor[idx]=run; run += deg[idx]; }
  }
  if (t == 0) indptr[NN] = ETOT;
}

__global__ void scatter_edges(const int* __restrict__ ei, int* __restrict__ cursor, int* __restrict__ csr_src){
  int e = blockIdx.x*256 + threadIdx.x;
  if (e >= ETOT) return;
  int s, d; edge_sd(ei, e, s, d);
  int pos = atomicAdd(cursor + d, 1);
  csr_src[pos] = s;
}

// ---------------- MFMA split-bf16 2-layer LSTM (80 nodes/block, single round) ----------------
// 1024 thr = 16 waves. Wave w owns gates w*16..w*16+15 (weights resident in VGPRs).
// Z = [x(0..31) | h0(32..95) | h1(96..159)] bf16 hi/lo in LDS [NB][ZROW].
// G exchange [gate][node][unit] f32, b128 writes. 4 barriers per timestep.
__global__ __launch_bounds__(1024, 4) void lstm_mfma(
    const float* __restrict__ x,
    const unsigned short* __restrict__ Wpk,
    const float* __restrict__ b0, const float* __restrict__ b1,
    float* __restrict__ h1out)
{
  __shared__ unsigned short Zh[NB*ZROW];   // 26.2 KB
  __shared__ unsigned short Zl[NB*ZROW];   // 26.2 KB
  __shared__ float G[4*NB*GST];            // 87.0 KB

  const int tid  = threadIdx.x;
  const int lane = tid & 63;
  const int w    = __builtin_amdgcn_readfirstlane(tid >> 6);   // 0..15
  const int ln15 = lane & 15;
  const int lq   = lane >> 4;                                  // 0..3
  const int gbase = blockIdx.x * NB;

  // ---- resident weight fragments ----
  const bf16x8* wp = (const bf16x8*)Wpk;
  bf16x8 wA0h[3], wA0l[3], wA1h[4], wA1l[4];
#pragma unroll
  for (int ks=0; ks<3; ++ks){
    wA0h[ks] = wp[((w*3 + ks)*2 + 0)*64 + lane];
    wA0l[ks] = wp[((w*3 + ks)*2 + 1)*64 + lane];
  }
#pragma unroll
  for (int ks=0; ks<4; ++ks){
    wA1h[ks] = wp[6144 + ((w*4 + ks)*2 + 0)*64 + lane];
    wA1l[ks] = wp[6144 + ((w*4 + ks)*2 + 1)*64 + lane];
  }
  float bv0[4], bv1[4];
#pragma unroll
  for (int r=0; r<4; ++r){
    bv0[r] = b0[w*16 + lq*4 + r];
    bv1[r] = b1[w*16 + lq*4 + r];
  }

  // pointwise mapping: thread -> unit pu (0..63), node-low ps; 5 nodes (16a+ps)
  const int pu = tid >> 4;
  const int ps = tid & 15;
  float c0[5], c1[5];
#pragma unroll
  for (int i=0;i<5;i++){ c0[i]=0.f; c1[i]=0.f; }

  // x staging: threads 0..639, node xn=tid>>3 (0..79), k-quad xk=(tid&7)*4
  const int xn = tid >> 3;
  const int xk = (tid & 7) * 4;
  const float* xbase = x + (size_t)(gbase + ((xn < NB) ? xn : 0))*(TT*INF_) + xk;
  const bool xth = (tid < 640);

  // G write bases: wave w -> gate qg, units ub..ub+3, nodes g*16+ln15
  const int qg = w >> 2;
  const int ub = (w & 3)*16 + lq*4;

  // ---- prologue: zero Z, stage x(0) ----
  for (int i = tid; i < NB*ZROW; i += 1024){ Zh[i] = 0; Zl[i] = 0; }
  __syncthreads();
  if (xth){
    const float4 xv = *(const float4*)(xbase + 0);
    unsigned short h_[4], l_[4];
    h_[0]=f2bf(xv.x); h_[1]=f2bf(xv.y); h_[2]=f2bf(xv.z); h_[3]=f2bf(xv.w);
    l_[0]=f2bf(xv.x-bf2f(h_[0])); l_[1]=f2bf(xv.y-bf2f(h_[1]));
    l_[2]=f2bf(xv.z-bf2f(h_[2])); l_[3]=f2bf(xv.w-bf2f(h_[3]));
    *(uint2*)&Zh[xn*ZROW + xk] = make_uint2((unsigned)h_[0]|((unsigned)h_[1]<<16), (unsigned)h_[2]|((unsigned)h_[3]<<16));
    *(uint2*)&Zl[xn*ZROW + xk] = make_uint2((unsigned)l_[0]|((unsigned)l_[1]<<16), (unsigned)l_[2]|((unsigned)l_[3]<<16));
  }
  __syncthreads();

#define ZFRAG(Zb, node, kz) ({                                            \
    const unsigned short* _p = &Zb[(node)*ZROW + (kz) + 4*lq];            \
    short4v _a = *(const short4v*)_p;                                     \
    short4v _b = *(const short4v*)(_p + 16);                              \
    __builtin_shufflevector(_a, _b, 0,1,2,3,4,5,6,7); })

#define MF(acc, A, B) acc = __builtin_amdgcn_mfma_f32_16x16x32_bf16((A),(B),(acc),0,0,0)

#define GRP(ACC, GG, KZ, WH, WL) {                                        \
    bf16x8 zh = ZFRAG(Zh, (GG)*16+ln15, KZ);                              \
    bf16x8 zl = ZFRAG(Zl, (GG)*16+ln15, KZ);                              \
    MF(ACC, WH, zh); MF(ACC, WH, zl); MF(ACC, WL, zh); }

  for (int t=0; t<TT; ++t){
    // ================= Phase A: L0 MFMA =================
    {
      f32x4 a0,a1,a2,a3,a4;
      a0=a1=a2=a3=a4=(f32x4){bv0[0],bv0[1],bv0[2],bv0[3]};
#pragma unroll
      for (int ks=0; ks<3; ++ks){
        const int kz = ks*32;
        const bf16x8 wh = wA0h[ks], wl = wA0l[ks];
        GRP(a0,0,kz,wh,wl); GRP(a1,1,kz,wh,wl); GRP(a2,2,kz,wh,wl);
        GRP(a3,3,kz,wh,wl); GRP(a4,4,kz,wh,wl);
      }
      *(f32x4*)&G[((qg*NB + 0*16+ln15)*GST + ub)] = a0;
      *(f32x4*)&G[((qg*NB + 1*16+ln15)*GST + ub)] = a1;
      *(f32x4*)&G[((qg*NB + 2*16+ln15)*GST + ub)] = a2;
      *(f32x4*)&G[((qg*NB + 3*16+ln15)*GST + ub)] = a3;
      *(f32x4*)&G[((qg*NB + 4*16+ln15)*GST + ub)] = a4;
    }
    __syncthreads();

    // ================= Phase B: pointwise L0 -> h0 =================
#pragma unroll
    for (int a=0; a<5; ++a){
      const int n = a*16 + ps;
      const float gi = G[(0*NB+n)*GST + pu];
      const float gf = G[(1*NB+n)*GST + pu];
      const float gg = G[(2*NB+n)*GST + pu];
      const float go = G[(3*NB+n)*GST + pu];
      const float cc = sigf(gf)*c0[a] + sigf(gi)*tanhf_(gg);
      c0[a] = cc;
      const float hv = sigf(go)*tanhf_(cc);
      const unsigned short hh = f2bf(hv);
      Zh[n*ZROW + 32 + pu] = hh;
      Zl[n*ZROW + 32 + pu] = f2bf(hv - bf2f(hh));
    }
    __syncthreads();

    // ================= Phase C: L1 MFMA (+ stage x(t+1)) =================
    {
      float4 xv;
      const bool dox = xth && (t+1 < TT);
      if (dox) xv = *(const float4*)(xbase + (t+1)*INF_);

      f32x4 a0,a1,a2,a3,a4;
      a0=a1=a2=a3=a4=(f32x4){bv1[0],bv1[1],bv1[2],bv1[3]};
#pragma unroll
      for (int ks=0; ks<4; ++ks){
        const int kz = 32 + ks*32;
        const bf16x8 wh = wA1h[ks], wl = wA1l[ks];
        GRP(a0,0,kz,wh,wl); GRP(a1,1,kz,wh,wl); GRP(a2,2,kz,wh,wl);
        GRP(a3,3,kz,wh,wl); GRP(a4,4,kz,wh,wl);
      }
      if (dox){
        unsigned short h_[4], l_[4];
        h_[0]=f2bf(xv.x); h_[1]=f2bf(xv.y); h_[2]=f2bf(xv.z); h_[3]=f2bf(xv.w);
        l_[0]=f2bf(xv.x-bf2f(h_[0])); l_[1]=f2bf(xv.y-bf2f(h_[1]));
        l_[2]=f2bf(xv.z-bf2f(h_[2])); l_[3]=f2bf(xv.w-bf2f(h_[3]));
        *(uint2*)&Zh[xn*ZROW + xk] = make_uint2((unsigned)h_[0]|((unsigned)h_[1]<<16), (unsigned)h_[2]|((unsigned)h_[3]<<16));
        *(uint2*)&Zl[xn*ZROW + xk] = make_uint2((unsigned)l_[0]|((unsigned)l_[1]<<16), (unsigned)l_[2]|((unsigned)l_[3]<<16));
      }
      *(f32x4*)&G[((qg*NB + 0*16+ln15)*GST + ub)] = a0;
      *(f32x4*)&G[((qg*NB + 1*16+ln15)*GST + ub)] = a1;
      *(f32x4*)&G[((qg*NB + 2*16+ln15)*GST + ub)] = a2;
      *(f32x4*)&G[((qg*NB + 3*16+ln15)*GST + ub)] = a3;
      *(f32x4*)&G[((qg*NB + 4*16+ln15)*GST + ub)] = a4;
    }
    __syncthreads();

    // ================= Phase D: pointwise L1 -> h1 =================
#pragma unroll
    for (int a=0; a<5; ++a){
      const int n = a*16 + ps;
      const float gi = G[(0*NB+n)*GST + pu];
      const float gf = G[(1*NB+n)*GST + pu];
      const float gg = G[(2*NB+n)*GST + pu];
      const float go = G[(3*NB+n)*GST + pu];
      const float cc = sigf(gf)*c1[a] + sigf(gi)*tanhf_(gg);
      c1[a] = cc;
      const float hv = sigf(go)*tanhf_(cc);
      const unsigned short hh = f2bf(hv);
      Zh[n*ZROW + 96 + pu] = hh;
      Zl[n*ZROW + 96 + pu] = f2bf(hv - bf2f(hh));
    }
    __syncthreads();
  }

  // ---- epilogue: coalesced h1 write ----
  for (int o = tid; o < NB*64; o += 1024){
    const int n = o >> 6, u = o & 63;
    h1out[(size_t)(gbase+n)*64 + u] = bf2f(Zh[n*ZROW + 96 + u]) + bf2f(Zl[n*ZROW + 96 + u]);
  }
#undef ZFRAG
#undef MF
#undef GRP
}

// ---------------- GAT layer 1 prep ----------------
__global__ __launch_bounds__(256) void gat1_prep(const float* __restrict__ h1, const float* __restrict__ W,
  const float* __restrict__ as_, const float* __restrict__ ad_,
  float* __restrict__ xh, float* __restrict__ als, float* __restrict__ ald)
{
  const int nb = blockIdx.x;
  const int o  = threadIdx.x;
  const int q  = o >> 6, u = o & 63;
  const float* hp = h1 + (size_t)nb*64;
  float acc = 0.f;
#pragma unroll 8
  for (int k=0;k<64;k++) acc = fmaf(hp[k], W[k*256 + o], acc);
  xh[(size_t)nb*256 + o] = acc;
  float ps = acc * as_[o];
  float pd = acc * ad_[o];
#pragma unroll
  for (int off=32; off>=1; off>>=1){ ps += __shfl_xor(ps, off); pd += __shfl_xor(pd, off); }
  if (u == 0){ als[nb*4 + q] = ps; ald[nb*4 + q] = pd; }
}

// ---------------- GAT1 gather + fused epilogue ----------------
__global__ __launch_bounds__(256) void gat1_gather(
  const int* __restrict__ indptr, const int* __restrict__ csr_src,
  const float* __restrict__ als, const float* __restrict__ ald,
  const float* __restrict__ xh,  const float* __restrict__ b1g,
  const float* __restrict__ w2,  const float* __restrict__ as2, const float* __restrict__ ad2,
  float* __restrict__ xh2, float* __restrict__ a2s, float* __restrict__ a2d)
{
  const int d = blockIdx.x*4 + (threadIdx.x >> 6);
  const int lane = threadIdx.x & 63;
  if (d >= NN) return;
  const int p0 = indptr[d], p1 = indptr[d+1];

  float aldv[4];
#pragma unroll
  for (int q=0;q<4;q++) aldv[q] = ald[d*4+q];

  float mx[4];
#pragma unroll
  for (int q=0;q<4;q++) mx[q] = -3.4e38f;
  for (int e=p0+lane; e<p1; e+=64){
    int s = csr_src[e];
#pragma unroll
    for (int q=0;q<4;q++){
      float ev = lrelu(als[s*4+q] + aldv[q]);
      mx[q] = fmaxf(mx[q], ev);
    }
  }
#pragma unroll
  for (int off=32; off>=1; off>>=1){
#pragma unroll
    for (int q=0;q<4;q++) mx[q] = fmaxf(mx[q], __shfl_xor(mx[q], off));
  }

  const int q = lane >> 4;
  const float mq = mx[q];
  const float aldq = aldv[q];
  float ax=0.f, ay=0.f, az=0.f, aw=0.f, den=0.f;
  int s_next = (p0 < p1) ? csr_src[p0] : 0;
  for (int e=p0; e<p1; ++e){
    const int s = s_next;
    if (e+1 < p1) s_next = csr_src[e+1];
    float ev = lrelu(als[s*4+q] + aldq);
    float ex = __expf(ev - mq);
    den += ex;
    float4 v = *(const float4*)(xh + (size_t)s*256 + lane*4);
    ax = fmaf(ex, v.x, ax); ay = fmaf(ex, v.y, ay);
    az = fmaf(ex, v.z, az); aw = fmaf(ex, v.w, aw);
  }
  const float rr = 1.0f/(den + 1e-16f);
  const int o = lane*4;
  float v0 = ax*rr + b1g[o+0];
  float v1 = ay*rr + b1g[o+1];
  float v2 = az*rr + b1g[o+2];
  float v3 = aw*rr + b1g[o+3];
  v0 = v0>0.f?v0:0.f; v1 = v1>0.f?v1:0.f; v2 = v2>0.f?v2:0.f; v3 = v3>0.f?v3:0.f;
  float part = v0*w2[o+0] + v1*w2[o+1] + v2*w2[o+2] + v3*w2[o+3];
#pragma unroll
  for (int off=32; off>=1; off>>=1) part += __shfl_xor(part, off);
  if (lane == 0){
    xh2[d] = part;
    a2s[d] = part * as2[0];
    a2d[d] = part * ad2[0];
  }
}

// ---------------- GAT2 gather ----------------
__global__ __launch_bounds__(256) void gat2_gather(
  const int* __restrict__ indptr, const int* __restrict__ csr_src,
  const float* __restrict__ a2s, const float* __restrict__ a2d,
  const float* __restrict__ xh2, const float* __restrict__ b2,
  float* __restrict__ out)
{
  const int d = blockIdx.x*4 + (threadIdx.x >> 6);
  const int lane = threadIdx.x & 63;
  if (d >= NN) return;
  const int p0 = indptr[d], p1 = indptr[d+1];
  const float add = a2d[d];

  float mx = -3.4e38f;
  for (int e=p0+lane; e<p1; e+=64){
    int s = csr_src[e];
    mx = fmaxf(mx, lrelu(a2s[s] + add));
  }
#pragma unroll
  for (int off=32; off>=1; off>>=1) mx = fmaxf(mx, __shfl_xor(mx, off));

  float den = 0.f, num = 0.f;
  for (int e=p0+lane; e<p1; e+=64){
    int s = csr_src[e];
    float ev = lrelu(a2s[s] + add);
    float ex = __expf(ev - mx);
    den += ex;
    num = fmaf(ex, xh2[s], num);
  }
#pragma unroll
  for (int off=32; off>=1; off>>=1){ den += __shfl_xor(den, off); num += __shfl_xor(num, off); }
  if (lane == 0) out[d] = num/(den + 1e-16f) + b2[0];
}

// ---------------- launcher ----------------
extern "C" void kernel_launch(void* const* d_in, const int* in_sizes, int n_in,
                              void* d_out, int out_size, void* d_ws, size_t ws_size,
                              hipStream_t stream)
{
  const float* x    = (const float*)d_in[0];
  const int*   ei   = (const int*)d_in[1];
  const float* Wih0 = (const float*)d_in[2];
  const float* Whh0 = (const float*)d_in[3];
  const float* bih0 = (const float*)d_in[4];
  const float* bhh0 = (const float*)d_in[5];
  const float* Wih1 = (const float*)d_in[6];
  const float* Whh1 = (const float*)d_in[7];
  const float* bih1 = (const float*)d_in[8];
  const float* bhh1 = (const float*)d_in[9];
  const float* g1w  = (const float*)d_in[10];
  const float* g1as = (const float*)d_in[11];
  const float* g1ad = (const float*)d_in[12];
  const float* g1b  = (const float*)d_in[13];
  const float* g2w  = (const float*)d_in[14];
  const float* g2as = (const float*)d_in[15];
  const float* g2ad = (const float*)d_in[16];
  const float* g2b  = (const float*)d_in[17];

  float* ws  = (float*)d_ws;
  unsigned short* Wpk = (unsigned short*)ws;   // 114688 shorts = 57344 f32 slots
  float* b0  = ws + 57344;            // 256
  float* b1  = b0 + 256;              // 256
  float* h1  = b1 + 256;              // 20000*64
  float* xh  = h1 + 1280000;          // 20000*256
  float* als = xh + 5120000;          // 80000
  float* ald = als + 80000;           // 80000
  float* xh2 = ald + 80000;           // 20000
  float* a2s = xh2 + 20000;           // 20000
  float* a2d = a2s + 20000;           // 20000
  int*   deg    = (int*)(a2d + 20000);   // 20000
  int*   indptr = deg + 20000;           // 20001
  int*   cursor = indptr + 20001;        // 20000
  int*   csr    = cursor + 20000;        // 340000

  kzero_int<<<(NN+255)/256, 256, 0, stream>>>(deg, NN);
  pack_weights<<<450, 256, 0, stream>>>(Wih0,Whh0,bih0,bhh0,Wih1,Whh1,bih1,bhh1,Wpk,b0,b1);
  count_deg<<<(ETOT+255)/256, 256, 0, stream>>>(ei, deg);
  scan_deg<<<1, 256, 0, stream>>>(deg, indptr, cursor);
  scatter_edges<<<(ETOT+255)/256, 256, 0, stream>>>(ei, cursor, csr);
  lstm_mfma<<<250, 1024, 0, stream>>>(x, Wpk, b0, b1, h1);
  gat1_prep<<<NN, 256, 0, stream>>>(h1, g1w, g1as, g1ad, xh, als, ald);
  gat1_gather<<<(NN+3)/4, 256, 0, stream>>>(indptr, csr, als, ald, xh, g1b, g2w, g2as, g2ad, xh2, a2s, a2d);
  gat2_gather<<<(NN+3)/4, 256, 0, stream>>>(indptr, csr, a2s, a2d, xh2, g2b, (float*)d_out);
}

// Round 6
// 601.305 us; speedup vs baseline: 13.1100x; 1.3177x over previous
//
#include <hip/hip_runtime.h>
#include <math.h>

#define NN   20000
#define TT   32
#define INF_ 32
#define HID  64
#define NH   4
#define EE   320000
#define ETOT (EE + NN)
#define ZROW 168   // shorts/row: 5 chunks x 32 + 8 pad; 336B rows (16B-aligned)
#define NB   80    // nodes per LSTM block; 250*80 = 20000 exact
#define GST  68    // G unit-stride dwords (64 + 4 pad)

typedef __attribute__((ext_vector_type(8))) short bf16x8;
typedef __attribute__((ext_vector_type(4))) float f32x4;

static __device__ __forceinline__ float sigf(float x){ return 1.0f/(1.0f+__expf(-x)); }
static __device__ __forceinline__ float tanhf_(float x){ float e=__expf(2.0f*x); return 1.0f - 2.0f/(e+1.0f); }
static __device__ __forceinline__ float lrelu(float x){ return x>0.0f ? x : 0.2f*x; }

static __device__ __forceinline__ unsigned short f2bf(float f){
  unsigned u = __float_as_uint(f);
  unsigned r = u + 0x7fffu + ((u>>16)&1u);
  return (unsigned short)(r>>16);
}
static __device__ __forceinline__ float bf2f(unsigned short h){ return __uint_as_float(((unsigned)h)<<16); }

static __device__ __forceinline__ void edge_sd(const int* __restrict__ ei, int e, int& s, int& d){
  if (e < EE){ s = ei[e]; d = ei[EE + e]; } else { s = e - EE; d = s; }
}

// chunk-local permuted position for k' (0..31): p = (k'&3) + 4*((k'>>4)&1) + 8*((k'>>2)&3)
static __device__ __forceinline__ int zpos(int kq){
  return (kq&3) + (((kq>>4)&1)<<2) + (((kq>>2)&3)<<3);
}

// ---------------- utility kernels ----------------
__global__ void kzero_int(int* __restrict__ p, int n){
  int i = blockIdx.x*256 + threadIdx.x;
  if (i < n) p[i] = 0;
}

// Pack weights into MFMA A-fragment layout (split bf16 hi/lo) + bias sums. (verified R3)
__global__ void pack_weights(const float* __restrict__ Wih0, const float* __restrict__ Whh0,
                             const float* __restrict__ bih0, const float* __restrict__ bhh0,
                             const float* __restrict__ Wih1, const float* __restrict__ Whh1,
                             const float* __restrict__ bih1, const float* __restrict__ bhh1,
                             unsigned short* __restrict__ Wpk,
                             float* __restrict__ b0, float* __restrict__ b1){
  int idx = blockIdx.x*256 + threadIdx.x;
  if (idx < 49152){
    int fb = idx >> 9;          // 0..95
    int h  = fb & 1;
    int t2 = fb >> 1;           // 0..47
    int ks = t2 % 3, w = t2 / 3;
    int r  = idx & 511;
    int l  = r >> 3, j = r & 7;
    int gate = w*16 + (l & 15);
    int k = ks*32 + 4*(l>>4) + (j & 3) + 16*(j >> 2);
    float src = (k < 32) ? Wih0[gate*32 + k] : Whh0[gate*64 + (k - 32)];
    unsigned short hi = f2bf(src);
    Wpk[idx] = h ? f2bf(src - bf2f(hi)) : hi;
  } else if (idx < 114688){
    int idx2 = idx - 49152;
    int fb = idx2 >> 9;         // 0..127
    int h  = fb & 1;
    int t2 = fb >> 1;           // 0..63
    int ks = t2 & 3, w = t2 >> 2;
    int r  = idx2 & 511;
    int l  = r >> 3, j = r & 7;
    int gate = w*16 + (l & 15);
    int k = ks*32 + 4*(l>>4) + (j & 3) + 16*(j >> 2);   // 0..127
    float src = (k < 64) ? Wih1[gate*64 + k] : Whh1[gate*64 + (k - 64)];
    unsigned short hi = f2bf(src);
    Wpk[idx] = h ? f2bf(src - bf2f(hi)) : hi;
  } else {
    int m = idx - 114688;
    if (m < 256) b0[m] = bih0[m] + bhh0[m];
    else if (m < 512) b1[m-256] = bih1[m-256] + bhh1[m-256];
  }
}

// ---------------- CSR build (dst-indexed) ----------------
__global__ void count_deg(const int* __restrict__ ei, int* __restrict__ deg){
  int e = blockIdx.x*256 + threadIdx.x;
  if (e >= ETOT) return;
  int s, d; edge_sd(ei, e, s, d);
  atomicAdd(deg + d, 1);
}

__global__ void scan_deg(const int* __restrict__ deg, int* __restrict__ indptr, int* __restrict__ cursor){
  __shared__ int part[256];
  const int t = threadIdx.x;
  const int CH = (NN + 255) / 256;
  const int c0 = t * CH;
  int sum = 0;
  for (int i=0;i<CH;i++){ int idx=c0+i; if (idx<NN) sum += deg[idx]; }
  part[t] = sum; __syncthreads();
  int val = sum;
  for (int off=1; off<256; off<<=1){
    int add = (t>=off) ? part[t-off] : 0;
    __syncthreads();
    val += add; part[t] = val;
    __syncthreads();
  }
  int run = val - sum;
  for (int i=0;i<CH;i++){
    int idx=c0+i;
    if (idx<NN){ indptr[idx]=run; cursor[idx]=run; run += deg[idx]; }
  }
  if (t == 0) indptr[NN] = ETOT;
}

__global__ void scatter_edges(const int* __restrict__ ei, int* __restrict__ cursor, int* __restrict__ csr_src){
  int e = blockIdx.x*256 + threadIdx.x;
  if (e >= ETOT) return;
  int s, d; edge_sd(ei, e, s, d);
  int pos = atomicAdd(cursor + d, 1);
  csr_src[pos] = s;
}

// ---------------- MFMA split-bf16 2-layer LSTM (80 nodes/block, 1 grid round) ----------------
// 16 waves; wave w owns gates w*16..+15, weights resident (amdgpu_waves_per_eu(4,4) -> 128 VGPR).
// Z rows permuted so each B-fragment is one ds_read_b128. x staged in pointwise phase B.
__global__ __launch_bounds__(1024)
__attribute__((amdgpu_waves_per_eu(4,4)))
void lstm_mfma(
    const float* __restrict__ x,
    const unsigned short* __restrict__ Wpk,
    const float* __restrict__ b0, const float* __restrict__ b1,
    float* __restrict__ h1out)
{
  __shared__ unsigned short Zh[NB*ZROW];   // 26.9 KB
  __shared__ unsigned short Zl[NB*ZROW];   // 26.9 KB
  __shared__ float G[4*NB*GST];            // 87.0 KB

  const int tid  = threadIdx.x;
  const int lane = tid & 63;
  const int w    = __builtin_amdgcn_readfirstlane(tid >> 6);   // 0..15
  const int ln15 = lane & 15;
  const int lq   = lane >> 4;                                  // 0..3
  const int gbase = blockIdx.x * NB;

  // ---- resident weight fragments ----
  const bf16x8* wp = (const bf16x8*)Wpk;
  bf16x8 wA0h[3], wA0l[3], wA1h[4], wA1l[4];
#pragma unroll
  for (int ks=0; ks<3; ++ks){
    wA0h[ks] = wp[((w*3 + ks)*2 + 0)*64 + lane];
    wA0l[ks] = wp[((w*3 + ks)*2 + 1)*64 + lane];
  }
#pragma unroll
  for (int ks=0; ks<4; ++ks){
    wA1h[ks] = wp[6144 + ((w*4 + ks)*2 + 0)*64 + lane];
    wA1l[ks] = wp[6144 + ((w*4 + ks)*2 + 1)*64 + lane];
  }
  float bv0[4], bv1[4];
#pragma unroll
  for (int r=0; r<4; ++r){
    bv0[r] = b0[w*16 + lq*4 + r];
    bv1[r] = b1[w*16 + lq*4 + r];
  }

  // pointwise mapping: unit pu = tid>>4, node-low ps = tid&15; 5 nodes (a*16+ps)
  const int pu = tid >> 4;
  const int ps = tid & 15;
  const int zo0 = (1 + (pu>>5))*32 + zpos(pu & 31);  // h0 slot for unit pu
  const int zo1 = zo0 + 64;                          // h1 slot (chunks 3,4)
  float c0[5], c1[5];
#pragma unroll
  for (int i=0;i<5;i++){ c0[i]=0.f; c1[i]=0.f; }

  // x staging: threads 0..639; node xn=tid>>3, k-quad xk=(tid&7)*4 -> permuted slot
  const int xn = tid >> 3;
  const int xk = (tid & 7) * 4;
  const int xslot = (((xk>>2)&3)<<3) + (((xk>>4)&1)<<2);  // chunk 0, 4-short slot
  const float* xbase = x + (size_t)(gbase + ((xn < NB) ? xn : 0))*(TT*INF_) + xk;
  const bool xth = (tid < 640);

  // G write: wave w -> gate qg, units ub..ub+3
  const int qg = w >> 2;
  const int ub = (w & 3)*16 + lq*4;

  // ---- prologue: zero Z, stage x(0) ----
  for (int i = tid; i < NB*ZROW; i += 1024){ Zh[i] = 0; Zl[i] = 0; }
  __syncthreads();
  if (xth){
    const float4 xv = *(const float4*)(xbase + 0);
    unsigned short h_[4], l_[4];
    h_[0]=f2bf(xv.x); h_[1]=f2bf(xv.y); h_[2]=f2bf(xv.z); h_[3]=f2bf(xv.w);
    l_[0]=f2bf(xv.x-bf2f(h_[0])); l_[1]=f2bf(xv.y-bf2f(h_[1]));
    l_[2]=f2bf(xv.z-bf2f(h_[2])); l_[3]=f2bf(xv.w-bf2f(h_[3]));
    *(uint2*)&Zh[xn*ZROW + xslot] = make_uint2((unsigned)h_[0]|((unsigned)h_[1]<<16), (unsigned)h_[2]|((unsigned)h_[3]<<16));
    *(uint2*)&Zl[xn*ZROW + xslot] = make_uint2((unsigned)l_[0]|((unsigned)l_[1]<<16), (unsigned)l_[2]|((unsigned)l_[3]<<16));
  }
  __syncthreads();

#define ZFRAG(Zb, node, ck) (*(const bf16x8*)&Zb[(node)*ZROW + (ck)*32 + lq*8])
#define MF(acc, A, B) acc = __builtin_amdgcn_mfma_f32_16x16x32_bf16((A),(B),(acc),0,0,0)
#define GRP(ACC, GG, CK, WH, WL) {                                        \
    bf16x8 zh = ZFRAG(Zh, (GG)*16+ln15, CK);                              \
    bf16x8 zl = ZFRAG(Zl, (GG)*16+ln15, CK);                              \
    MF(ACC, WH, zh); MF(ACC, WH, zl); MF(ACC, WL, zh); }

  for (int t=0; t<TT; ++t){
    // ================= Phase A: L0 MFMA (chunks 0..2) =================
    {
      f32x4 a0,a1,a2,a3,a4;
      a0=a1=a2=a3=a4=(f32x4){bv0[0],bv0[1],bv0[2],bv0[3]};
#pragma unroll
      for (int ks=0; ks<3; ++ks){
        const bf16x8 wh = wA0h[ks], wl = wA0l[ks];
        GRP(a0,0,ks,wh,wl); GRP(a1,1,ks,wh,wl); GRP(a2,2,ks,wh,wl);
        GRP(a3,3,ks,wh,wl); GRP(a4,4,ks,wh,wl);
      }
      *(f32x4*)&G[((qg*NB + 0*16+ln15)*GST + ub)] = a0;
      *(f32x4*)&G[((qg*NB + 1*16+ln15)*GST + ub)] = a1;
      *(f32x4*)&G[((qg*NB + 2*16+ln15)*GST + ub)] = a2;
      *(f32x4*)&G[((qg*NB + 3*16+ln15)*GST + ub)] = a3;
      *(f32x4*)&G[((qg*NB + 4*16+ln15)*GST + ub)] = a4;
    }
    __syncthreads();

    // ================= Phase B: pointwise L0 -> h0, stage x(t+1) =================
    {
      float4 xv;
      const bool dox = xth && (t+1 < TT);
      if (dox) xv = *(const float4*)(xbase + (size_t)(t+1)*INF_);
#pragma unroll
      for (int a=0; a<5; ++a){
        const int n = a*16 + ps;
        const float gi = G[(0*NB+n)*GST + pu];
        const float gf = G[(1*NB+n)*GST + pu];
        const float gg = G[(2*NB+n)*GST + pu];
        const float go = G[(3*NB+n)*GST + pu];
        const float cc = sigf(gf)*c0[a] + sigf(gi)*tanhf_(gg);
        c0[a] = cc;
        const float hv = sigf(go)*tanhf_(cc);
        const unsigned short hh = f2bf(hv);
        Zh[n*ZROW + zo0] = hh;
        Zl[n*ZROW + zo0] = f2bf(hv - bf2f(hh));
      }
      if (dox){
        unsigned short h_[4], l_[4];
        h_[0]=f2bf(xv.x); h_[1]=f2bf(xv.y); h_[2]=f2bf(xv.z); h_[3]=f2bf(xv.w);
        l_[0]=f2bf(xv.x-bf2f(h_[0])); l_[1]=f2bf(xv.y-bf2f(h_[1]));
        l_[2]=f2bf(xv.z-bf2f(h_[2])); l_[3]=f2bf(xv.w-bf2f(h_[3]));
        *(uint2*)&Zh[xn*ZROW + xslot] = make_uint2((unsigned)h_[0]|((unsigned)h_[1]<<16), (unsigned)h_[2]|((unsigned)h_[3]<<16));
        *(uint2*)&Zl[xn*ZROW + xslot] = make_uint2((unsigned)l_[0]|((unsigned)l_[1]<<16), (unsigned)l_[2]|((unsigned)l_[3]<<16));
      }
    }
    __syncthreads();

    // ================= Phase C: L1 MFMA (chunks 1..4) =================
    {
      f32x4 a0,a1,a2,a3,a4;
      a0=a1=a2=a3=a4=(f32x4){bv1[0],bv1[1],bv1[2],bv1[3]};
#pragma unroll
      for (int ks=0; ks<4; ++ks){
        const bf16x8 wh = wA1h[ks], wl = wA1l[ks];
        GRP(a0,0,1+ks,wh,wl); GRP(a1,1,1+ks,wh,wl); GRP(a2,2,1+ks,wh,wl);
        GRP(a3,3,1+ks,wh,wl); GRP(a4,4,1+ks,wh,wl);
      }
      *(f32x4*)&G[((qg*NB + 0*16+ln15)*GST + ub)] = a0;
      *(f32x4*)&G[((qg*NB + 1*16+ln15)*GST + ub)] = a1;
      *(f32x4*)&G[((qg*NB + 2*16+ln15)*GST + ub)] = a2;
      *(f32x4*)&G[((qg*NB + 3*16+ln15)*GST + ub)] = a3;
      *(f32x4*)&G[((qg*NB + 4*16+ln15)*GST + ub)] = a4;
    }
    __syncthreads();

    // ================= Phase D: pointwise L1 -> h1 =================
#pragma unroll
    for (int a=0; a<5; ++a){
      const int n = a*16 + ps;
      const float gi = G[(0*NB+n)*GST + pu];
      const float gf = G[(1*NB+n)*GST + pu];
      const float gg = G[(2*NB+n)*GST + pu];
      const float go = G[(3*NB+n)*GST + pu];
      const float cc = sigf(gf)*c1[a] + sigf(gi)*tanhf_(gg);
      c1[a] = cc;
      const float hv = sigf(go)*tanhf_(cc);
      const unsigned short hh = f2bf(hv);
      Zh[n*ZROW + zo1] = hh;
      Zl[n*ZROW + zo1] = f2bf(hv - bf2f(hh));
    }
    __syncthreads();
  }

  // ---- epilogue: coalesced h1 write (permuted read) ----
  for (int o = tid; o < NB*64; o += 1024){
    const int n = o >> 6, u = o & 63;
    const int zp = (3 + (u>>5))*32 + zpos(u & 31);
    h1out[(size_t)(gbase+n)*64 + u] = bf2f(Zh[n*ZROW + zp]) + bf2f(Zl[n*ZROW + zp]);
  }
#undef ZFRAG
#undef MF
#undef GRP
}

// ---------------- GAT layer 1 prep ----------------
__global__ __launch_bounds__(256) void gat1_prep(const float* __restrict__ h1, const float* __restrict__ W,
  const float* __restrict__ as_, const float* __restrict__ ad_,
  float* __restrict__ xh, float* __restrict__ als, float* __restrict__ ald)
{
  const int nb = blockIdx.x;
  const int o  = threadIdx.x;
  const int q  = o >> 6, u = o & 63;
  const float* hp = h1 + (size_t)nb*64;
  float acc = 0.f;
#pragma unroll 8
  for (int k=0;k<64;k++) acc = fmaf(hp[k], W[k*256 + o], acc);
  xh[(size_t)nb*256 + o] = acc;
  float ps = acc * as_[o];
  float pd = acc * ad_[o];
#pragma unroll
  for (int off=32; off>=1; off>>=1){ ps += __shfl_xor(ps, off); pd += __shfl_xor(pd, off); }
  if (u == 0){ als[nb*4 + q] = ps; ald[nb*4 + q] = pd; }
}

// ---------------- GAT1 gather + fused epilogue ----------------
__global__ __launch_bounds__(256) void gat1_gather(
  const int* __restrict__ indptr, const int* __restrict__ csr_src,
  const float* __restrict__ als, const float* __restrict__ ald,
  const float* __restrict__ xh,  const float* __restrict__ b1g,
  const float* __restrict__ w2,  const float* __restrict__ as2, const float* __restrict__ ad2,
  float* __restrict__ xh2, float* __restrict__ a2s, float* __restrict__ a2d)
{
  const int d = blockIdx.x*4 + (threadIdx.x >> 6);
  const int lane = threadIdx.x & 63;
  if (d >= NN) return;
  const int p0 = indptr[d], p1 = indptr[d+1];

  float aldv[4];
#pragma unroll
  for (int q=0;q<4;q++) aldv[q] = ald[d*4+q];

  float mx[4];
#pragma unroll
  for (int q=0;q<4;q++) mx[q] = -3.4e38f;
  for (int e=p0+lane; e<p1; e+=64){
    int s = csr_src[e];
#pragma unroll
    for (int q=0;q<4;q++){
      float ev = lrelu(als[s*4+q] + aldv[q]);
      mx[q] = fmaxf(mx[q], ev);
    }
  }
#pragma unroll
  for (int off=32; off>=1; off>>=1){
#pragma unroll
    for (int q=0;q<4;q++) mx[q] = fmaxf(mx[q], __shfl_xor(mx[q], off));
  }

  const int q = lane >> 4;
  const float mq = mx[q];
  const float aldq = aldv[q];
  float ax=0.f, ay=0.f, az=0.f, aw=0.f, den=0.f;
  int s_next = (p0 < p1) ? csr_src[p0] : 0;
  for (int e=p0; e<p1; ++e){
    const int s = s_next;
    if (e+1 < p1) s_next = csr_src[e+1];
    float ev = lrelu(als[s*4+q] + aldq);
    float ex = __expf(ev - mq);
    den += ex;
    float4 v = *(const float4*)(xh + (size_t)s*256 + lane*4);
    ax = fmaf(ex, v.x, ax); ay = fmaf(ex, v.y, ay);
    az = fmaf(ex, v.z, az); aw = fmaf(ex, v.w, aw);
  }
  const float rr = 1.0f/(den + 1e-16f);
  const int o = lane*4;
  float v0 = ax*rr + b1g[o+0];
  float v1 = ay*rr + b1g[o+1];
  float v2 = az*rr + b1g[o+2];
  float v3 = aw*rr + b1g[o+3];
  v0 = v0>0.f?v0:0.f; v1 = v1>0.f?v1:0.f; v2 = v2>0.f?v2:0.f; v3 = v3>0.f?v3:0.f;
  float part = v0*w2[o+0] + v1*w2[o+1] + v2*w2[o+2] + v3*w2[o+3];
#pragma unroll
  for (int off=32; off>=1; off>>=1) part += __shfl_xor(part, off);
  if (lane == 0){
    xh2[d] = part;
    a2s[d] = part * as2[0];
    a2d[d] = part * ad2[0];
  }
}

// ---------------- GAT2 gather ----------------
__global__ __launch_bounds__(256) void gat2_gather(
  const int* __restrict__ indptr, const int* __restrict__ csr_src,
  const float* __restrict__ a2s, const float* __restrict__ a2d,
  const float* __restrict__ xh2, const float* __restrict__ b2,
  float* __restrict__ out)
{
  const int d = blockIdx.x*4 + (threadIdx.x >> 6);
  const int lane = threadIdx.x & 63;
  if (d >= NN) return;
  const int p0 = indptr[d], p1 = indptr[d+1];
  const float add = a2d[d];

  float mx = -3.4e38f;
  for (int e=p0+lane; e<p1; e+=64){
    int s = csr_src[e];
    mx = fmaxf(mx, lrelu(a2s[s] + add));
  }
#pragma unroll
  for (int off=32; off>=1; off>>=1) mx = fmaxf(mx, __shfl_xor(mx, off));

  float den = 0.f, num = 0.f;
  for (int e=p0+lane; e<p1; e+=64){
    int s = csr_src[e];
    float ev = lrelu(a2s[s] + add);
    float ex = __expf(ev - mx);
    den += ex;
    num = fmaf(ex, xh2[s], num);
  }
#pragma unroll
  for (int off=32; off>=1; off>>=1){ den += __shfl_xor(den, off); num += __shfl_xor(num, off); }
  if (lane == 0) out[d] = num/(den + 1e-16f) + b2[0];
}

// ---------------- launcher ----------------
extern "C" void kernel_launch(void* const* d_in, const int* in_sizes, int n_in,
                              void* d_out, int out_size, void* d_ws, size_t ws_size,
                              hipStream_t stream)
{
  const float* x    = (const float*)d_in[0];
  const int*   ei   = (const int*)d_in[1];
  const float* Wih0 = (const float*)d_in[2];
  const float* Whh0 = (const float*)d_in[3];
  const float* bih0 = (const float*)d_in[4];
  const float* bhh0 = (const float*)d_in[5];
  const float* Wih1 = (const float*)d_in[6];
  const float* Whh1 = (const float*)d_in[7];
  const float* bih1 = (const float*)d_in[8];
  const float* bhh1 = (const float*)d_in[9];
  const float* g1w  = (const float*)d_in[10];
  const float* g1as = (const float*)d_in[11];
  const float* g1ad = (const float*)d_in[12];
  const float* g1b  = (const float*)d_in[13];
  const float* g2w  = (const float*)d_in[14];
  const float* g2as = (const float*)d_in[15];
  const float* g2ad = (const float*)d_in[16];
  const float* g2b  = (const float*)d_in[17];

  float* ws  = (float*)d_ws;
  unsigned short* Wpk = (unsigned short*)ws;   // 114688 shorts = 57344 f32 slots
  float* b0  = ws + 57344;            // 256
  float* b1  = b0 + 256;              // 256
  float* h1  = b1 + 256;              // 20000*64
  float* xh  = h1 + 1280000;          // 20000*256
  float* als = xh + 5120000;          // 80000
  float* ald = als + 80000;           // 80000
  float* xh2 = ald + 80000;           // 20000
  float* a2s = xh2 + 20000;           // 20000
  float* a2d = a2s + 20000;           // 20000
  int*   deg    = (int*)(a2d + 20000);   // 20000
  int*   indptr = deg + 20000;           // 20001
  int*   cursor = indptr + 20001;        // 20000
  int*   csr    = cursor + 20000;        // 340000

  kzero_int<<<(NN+255)/256, 256, 0, stream>>>(deg, NN);
  pack_weights<<<450, 256, 0, stream>>>(Wih0,Whh0,bih0,bhh0,Wih1,Whh1,bih1,bhh1,Wpk,b0,b1);
  count_deg<<<(ETOT+255)/256, 256, 0, stream>>>(ei, deg);
  scan_deg<<<1, 256, 0, stream>>>(deg, indptr, cursor);
  scatter_edges<<<(ETOT+255)/256, 256, 0, stream>>>(ei, cursor, csr);
  lstm_mfma<<<250, 1024, 0, stream>>>(x, Wpk, b0, b1, h1);
  gat1_prep<<<NN, 256, 0, stream>>>(h1, g1w, g1as, g1ad, xh, als, ald);
  gat1_gather<<<(NN+3)/4, 256, 0, stream>>>(indptr, csr, als, ald, xh, g1b, g2w, g2as, g2ad, xh2, a2s, a2d);
  gat2_gather<<<(NN+3)/4, 256, 0, stream>>>(indptr, csr, a2s, a2d, xh2, g2b, (float*)d_out);
}